// Round 3
// baseline (632.545 us; speedup 1.0000x reference)
//
#include <hip/hip_runtime.h>
#include <hip/hip_bf16.h>
#include <math.h>

#define N_NODES 20000
#define N_EDGES 320000
#define IN_DIM 128
#define HID 256
#define HEADS 8
#define DH 32
#define LAYERS 3
#define NUM_GRAPHS 64
#define OUT_DIM 10
#define SLOPE 0.2f

// src-bucketed CSR: bucket = src >> 12 (4096 nodes = 2 MB of fsb per bucket)
#define NBKT 5
#define N_BINS (N_NODES * NBKT)      // 100000
#define N_BINS4 (N_BINS / 4)         // 25000
#define N_CHUNK 98                   // ceil(100000 / 1024) chunks of 1024 bins

#define GEMM_TILES 626               // 313 m-tiles x 2 n-tiles
#define COUNT_BLOCKS 1250            // 320000 / 256

typedef __bf16 bf16x8 __attribute__((ext_vector_type(8)));
typedef float f32x4 __attribute__((ext_vector_type(4)));

static __device__ __forceinline__ unsigned short f2bfbits(float v) {
    __bf16 b = (__bf16)v;
    return __builtin_bit_cast(unsigned short, b);
}
// unpack 8 bf16 (in a uint4) -> 8 fp32, exact
static __device__ __forceinline__ void unpack8(uint4 u, float* f) {
    unsigned p0 = u.x, p1 = u.y, p2 = u.z, p3 = u.w;
    f[0] = __builtin_bit_cast(float, p0 << 16);
    f[1] = __builtin_bit_cast(float, p0 & 0xffff0000u);
    f[2] = __builtin_bit_cast(float, p1 << 16);
    f[3] = __builtin_bit_cast(float, p1 & 0xffff0000u);
    f[4] = __builtin_bit_cast(float, p2 << 16);
    f[5] = __builtin_bit_cast(float, p2 & 0xffff0000u);
    f[6] = __builtin_bit_cast(float, p3 << 16);
    f[7] = __builtin_bit_cast(float, p3 & 0xffff0000u);
}

// async 16B global->LDS (DMA, wave-uniform LDS base + lane*16)
typedef const __attribute__((address_space(1))) unsigned int* as1_u32p;
typedef __attribute__((address_space(3))) unsigned int* as3_u32p;
static __device__ __forceinline__ void async_cp16(const unsigned short* g, unsigned short* l) {
    __builtin_amdgcn_global_load_lds((as1_u32p)g, (as3_u32p)l, 16, 0, 0);
}

// ---------------- prep: feature cast, weight transpose/cast ----------------
#define CAST_N4 (N_NODES * IN_DIM / 4)                 // 640000
#define WTRANS_TOTAL (IN_DIM * HID + 6 * HID * HID)    // 425984
#define PREP_TOTAL (CAST_N4 + WTRANS_TOTAL)            // 1065984 = 4164 * 256
#define PREP_BLOCKS (PREP_TOTAL / 256)                 // 4164 (exact)

static __device__ void prep_item(int idx,
                                 const float* __restrict__ feat,
                                 const float* __restrict__ Win,
                                 const float* __restrict__ Wsrc,
                                 const float* __restrict__ Wdst,
                                 unsigned short* __restrict__ featH,
                                 unsigned short* __restrict__ WinT,
                                 unsigned short* __restrict__ WT) {
    if (idx < CAST_N4) {
        float4 v = ((const float4*)feat)[idx];
        ushort4 o;
        o.x = f2bfbits(v.x); o.y = f2bfbits(v.y);
        o.z = f2bfbits(v.z); o.w = f2bfbits(v.w);
        ((ushort4*)featH)[idx] = o;
    } else {
        int j = idx - CAST_N4;
        if (j < IN_DIM * HID) {
            int n = j / IN_DIM, k = j % IN_DIM;
            WinT[j] = f2bfbits(Win[k * HID + n]);
        } else {
            int r6 = j - IN_DIM * HID;
            int mat = r6 >> 16;
            int r = r6 & 65535;
            int n = r >> 8, k = r & 255;
            const float* base = (mat < 3) ? (Wsrc + (size_t)mat * 65536)
                                          : (Wdst + (size_t)(mat - 3) * 65536);
            WT[r6] = f2bfbits(base[k * 256 + n]);
        }
    }
}

// ---------------- wide scan: block u scans bins [1024u, 1024(u+1)) using bsum prefix ----------------
// bsum[i] = total count of chunk i (accumulated by count's second atomic).
static __device__ void scans_unit(int u, int t, const int* __restrict__ cnt,
                                  const int* __restrict__ bsum, int* __restrict__ offs,
                                  int* __restrict__ cursor, int* si) {
    // base = sum of bsum[0..u)   (u <= 97 < 256)
    int bv = (t < u) ? bsum[t] : 0;
#pragma unroll
    for (int d = 1; d < 64; d <<= 1) bv += __shfl_xor(bv, d, 64);
    if ((t & 63) == 0) si[t >> 6] = bv;
    __syncthreads();
    int base = si[0] + si[1] + si[2] + si[3];

    // local int4 scan of this chunk's 1024 bins
    int idx4 = u * 256 + t;
    int4 x = make_int4(0, 0, 0, 0);
    if (idx4 < N_BINS4) x = ((const int4*)cnt)[idx4];
    int tsum = x.x + x.y + x.z + x.w;
    int v = tsum;
#pragma unroll
    for (int d = 1; d < 64; d <<= 1) {
        int w = __shfl_up(v, d, 64);
        if ((t & 63) >= d) v += w;
    }
    if ((t & 63) == 63) si[4 + (t >> 6)] = v;
    __syncthreads();
    int wid = t >> 6;
    int waveoff = 0;
    if (wid > 0) waveoff += si[4];
    if (wid > 1) waveoff += si[5];
    if (wid > 2) waveoff += si[6];
    int ex = base + waveoff + (v - tsum);
    if (idx4 < N_BINS4) {
        int4 o;
        o.x = ex; o.y = ex + x.x; o.z = o.y + x.y; o.w = o.z + x.z;
        ((int4*)offs)[idx4] = o;
        ((int4*)cursor)[idx4] = o;
        if (idx4 == N_BINS4 - 1) offs[N_BINS] = ex + tsum;
    }
}

// ---------------- MFMA GEMM tile: bf16 A, M64 x N128, BK=32 (proven code) ----------------
template <int DUAL>
static __device__ void gemm_tile(int mt, int nt, int t,
                                 const unsigned short* __restrict__ Ah,
                                 const unsigned short* __restrict__ BT1,
                                 const float* __restrict__ bias1,
                                 unsigned short* __restrict__ O1,
                                 const unsigned short* __restrict__ BT2,
                                 const float* __restrict__ bias2,
                                 unsigned short* __restrict__ O2,
                                 int M, int K, int N,
                                 unsigned short* AsP, unsigned short* Bs1P,
                                 unsigned short* Bs2P) {
    const int wv = t >> 6, lane = t & 63, quad = lane >> 4, l15 = lane & 15;
    const int m0 = mt * 64, n0 = nt * 128;

    const int sA = wv * 64 + lane;
    const int rA = sA >> 2, cA = (sA & 3) ^ ((rA >> 1) & 3);
    int gmA = m0 + rA; if (gmA >= M) gmA = M - 1;
    const size_t offA = (size_t)gmA * K + cA * 8;
    const int sB0 = wv * 64 + lane, sB1v = sB0 + 256;
    const int rB0 = sB0 >> 2, cB0 = (sB0 & 3) ^ ((rB0 >> 1) & 3);
    const int rB1 = sB1v >> 2, cB1 = (sB1v & 3) ^ ((rB1 >> 1) & 3);
    const size_t offB0 = (size_t)(n0 + rB0) * K + cB0 * 8;
    const size_t offB1 = (size_t)(n0 + rB1) * K + cB1 * 8;

    auto issue = [&](int buf, int k0) {
        async_cp16(Ah + offA + k0, AsP + buf * 2048 + wv * 512);
        async_cp16(BT1 + offB0 + k0, Bs1P + buf * 4096 + wv * 512);
        async_cp16(BT1 + offB1 + k0, Bs1P + buf * 4096 + 2048 + wv * 512);
        if (DUAL) {
            async_cp16(BT2 + offB0 + k0, Bs2P + buf * 4096 + wv * 512);
            async_cp16(BT2 + offB1 + k0, Bs2P + buf * 4096 + 2048 + wv * 512);
        }
    };

    const int mrow0 = (wv >> 1) * 32;
    const int ncb = (wv & 1) * 64;

    f32x4 zero = {0.f, 0.f, 0.f, 0.f};
    f32x4 acc1[2][4], acc2[2][4];
#pragma unroll
    for (int mi = 0; mi < 2; ++mi)
#pragma unroll
        for (int t4 = 0; t4 < 4; ++t4) { acc1[mi][t4] = zero; acc2[mi][t4] = zero; }

    issue(0, 0);
    int buf = 0;
    for (int k0 = 0; k0 < K; k0 += 32, buf ^= 1) {
        __syncthreads();
        if (k0 + 32 < K) issue(buf ^ 1, k0 + 32);

        bf16x8 aF[2];
#pragma unroll
        for (int mi = 0; mi < 2; ++mi) {
            int row = mrow0 + mi * 16 + l15;
            int aoff = row * 32 + ((quad ^ ((row >> 1) & 3)) << 3);
            aF[mi] = __builtin_bit_cast(bf16x8, *(const uint4*)(AsP + buf * 2048 + aoff));
        }
#pragma unroll
        for (int t4 = 0; t4 < 4; ++t4) {
            int brow = ncb + t4 * 16 + l15;
            int boff = brow * 32 + ((quad ^ ((brow >> 1) & 3)) << 3);
            bf16x8 b1 = __builtin_bit_cast(bf16x8, *(const uint4*)(Bs1P + buf * 4096 + boff));
#pragma unroll
            for (int mi = 0; mi < 2; ++mi)
                acc1[mi][t4] = __builtin_amdgcn_mfma_f32_16x16x32_bf16(aF[mi], b1, acc1[mi][t4], 0, 0, 0);
            if (DUAL) {
                bf16x8 b2 = __builtin_bit_cast(bf16x8, *(const uint4*)(Bs2P + buf * 4096 + boff));
#pragma unroll
                for (int mi = 0; mi < 2; ++mi)
                    acc2[mi][t4] = __builtin_amdgcn_mfma_f32_16x16x32_bf16(aF[mi], b2, acc2[mi][t4], 0, 0, 0);
            }
        }
    }

    float bia1[4], bia2[4];
#pragma unroll
    for (int t4 = 0; t4 < 4; ++t4) {
        bia1[t4] = bias1[n0 + ncb + t4 * 16 + l15];
        bia2[t4] = DUAL ? bias2[n0 + ncb + t4 * 16 + l15] : 0.f;
    }
#pragma unroll
    for (int mi = 0; mi < 2; ++mi) {
#pragma unroll
        for (int t4 = 0; t4 < 4; ++t4) {
            int gn = n0 + ncb + t4 * 16 + l15;
#pragma unroll
            for (int r = 0; r < 4; ++r) {
                int gm = m0 + mrow0 + mi * 16 + quad * 4 + r;
                if (gm < M) {
                    float v = acc1[mi][t4][r] + bia1[t4];
                    O1[(size_t)gm * N + gn] = f2bfbits(v);
                    if (DUAL) {
                        float v2 = acc2[mi][t4][r] + bia2[t4];
                        O2[(size_t)gm * N + gn] = f2bfbits(v2);
                    }
                }
            }
        }
    }
}

// ---------------- GATv2 aggregation (proven code, 8 nodes / 256 threads) ----------------
static __device__ void agg_unit(int u, int t,
                                const unsigned short* __restrict__ fsb,
                                const unsigned short* __restrict__ fdb,
                                unsigned short* __restrict__ hb,
                                const int* __restrict__ offs,
                                const int* __restrict__ csr_src,
                                const float* __restrict__ attn_l) {
    int node = u * 8 + (t >> 5);
    if (node >= N_NODES) return;
    int l32 = t & 31;
    int dbase = l32 * 8;
    int abase = (l32 >> 2) * DH + (l32 & 3) * 8;

    float a[8];
#pragma unroll
    for (int j = 0; j < 8; ++j) a[j] = attn_l[abase + j];

    float fdv[8];
    unpack8(*(const uint4*)(fdb + (size_t)node * HID + dbase), fdv);

    float ssum0 = 0.f, ssum1 = 0.f;
    float acc0[8], acc1[8];
#pragma unroll
    for (int j = 0; j < 8; ++j) { acc0[j] = 0.f; acc1[j] = 0.f; }

    auto procE = [&](uint4 uu, float* acc, float& ssum) {
        float fsv[8];
        unpack8(uu, fsv);
        float p = 0.f;
#pragma unroll
        for (int j = 0; j < 8; ++j) {
            float e = fsv[j] + fdv[j];
            e = fmaxf(e, SLOPE * e);   // leakyrelu (slope<1)
            p += e * a[j];
        }
        p += __shfl_xor(p, 1, 64);
        p += __shfl_xor(p, 2, 64);
        float w = __expf(p);
        ssum += w;
#pragma unroll
        for (int j = 0; j < 8; ++j) acc[j] += w * fsv[j];
    };

    const unsigned short* fsl = fsb + dbase;
    int beg = offs[node * NBKT], end = offs[node * NBKT + NBKT];
    int nfull = (end - beg) >> 2;
    const int limit = beg + nfull * 4;

    uint4 cu0, cu1, cu2, cu3;
    int ci0, ci1, ci2, ci3;
    int base = beg + 8;
    bool have = (nfull >= 1);
    bool haveN = (nfull >= 2);
    if (have) {
        int s0 = csr_src[beg], s1 = csr_src[beg + 1];
        int s2 = csr_src[beg + 2], s3 = csr_src[beg + 3];
        if (haveN) {
            ci0 = csr_src[beg + 4]; ci1 = csr_src[beg + 5];
            ci2 = csr_src[beg + 6]; ci3 = csr_src[beg + 7];
        }
        cu0 = *(const uint4*)(fsl + (size_t)s0 * HID);
        cu1 = *(const uint4*)(fsl + (size_t)s1 * HID);
        cu2 = *(const uint4*)(fsl + (size_t)s2 * HID);
        cu3 = *(const uint4*)(fsl + (size_t)s3 * HID);
    }
    while (have) {
        uint4 nu0, nu1, nu2, nu3;
        int ni0, ni1, ni2, ni3;
        if (haveN) {
            nu0 = *(const uint4*)(fsl + (size_t)ci0 * HID);
            nu1 = *(const uint4*)(fsl + (size_t)ci1 * HID);
            nu2 = *(const uint4*)(fsl + (size_t)ci2 * HID);
            nu3 = *(const uint4*)(fsl + (size_t)ci3 * HID);
        }
        bool haveNN = (base + 4 <= limit);
        if (haveNN) {
            ni0 = csr_src[base]; ni1 = csr_src[base + 1];
            ni2 = csr_src[base + 2]; ni3 = csr_src[base + 3];
        }
        base += 4;
        procE(cu0, acc0, ssum0);
        procE(cu1, acc1, ssum1);
        procE(cu2, acc0, ssum0);
        procE(cu3, acc1, ssum1);
        if (haveN) { cu0 = nu0; cu1 = nu1; cu2 = nu2; cu3 = nu3; }
        if (haveNN) { ci0 = ni0; ci1 = ni1; ci2 = ni2; ci3 = ni3; }
        have = haveN; haveN = haveNN;
    }
    for (int idx = limit; idx < end; ++idx) {
        int sv = csr_src[idx];
        procE(*(const uint4*)(fsl + (size_t)sv * HID), acc0, ssum0);
    }

    float ssum = ssum0 + ssum1;
    float acc[8];
#pragma unroll
    for (int j = 0; j < 8; ++j) acc[j] = acc0[j] + acc1[j];

    float inv = ssum > 0.f ? 1.f / ssum : 0.f;
    float hv[8];
    unpack8(*(const uint4*)(hb + (size_t)node * HID + dbase), hv);
    unsigned short ob[8];
#pragma unroll
    for (int j = 0; j < 8; ++j) {
        float o = fmaxf(acc[j] * inv + hv[j], 0.f);
        ob[j] = f2bfbits(o);
    }
    *(uint4*)(hb + (size_t)node * HID + dbase) = *(uint4*)ob;
}

// ---------------- D1: prep || count (count also accumulates per-chunk totals) ----------------
__global__ void prep_count_kernel(const float* __restrict__ feat,
                                  const float* __restrict__ Win,
                                  const float* __restrict__ Wsrc,
                                  const float* __restrict__ Wdst,
                                  unsigned short* __restrict__ featH,
                                  unsigned short* __restrict__ WinT,
                                  unsigned short* __restrict__ WT,
                                  const int* __restrict__ src,
                                  const int* __restrict__ dst,
                                  int* __restrict__ cnt,
                                  int* __restrict__ bsum) {
    int bid = blockIdx.x;
    if (bid < PREP_BLOCKS) {
        prep_item(bid * 256 + threadIdx.x, feat, Win, Wsrc, Wdst, featH, WinT, WT);
    } else {
        int e = (bid - PREP_BLOCKS) * 256 + threadIdx.x;
        if (e < N_EDGES) {
            int bin = dst[e] * NBKT + (src[e] >> 12);
            atomicAdd(&cnt[bin], 1);
            atomicAdd(&bsum[bin >> 10], 1);   // per-1024-bin chunk total
        }
    }
}

// ---------------- D2: input-projection GEMM || wide scan (98 blocks) ----------------
__global__ __launch_bounds__(256, 4) void gemm0_scan_kernel(
    const unsigned short* __restrict__ featH, const unsigned short* __restrict__ WinT,
    const float* __restrict__ b_in, unsigned short* __restrict__ hb,
    const int* __restrict__ cnt, const int* __restrict__ bsum,
    int* __restrict__ offs, int* __restrict__ cursor) {
    __shared__ __align__(16) unsigned short smem[20480];
    int bid = blockIdx.x;
    if (bid < GEMM_TILES) {
        gemm_tile<0>(bid >> 1, bid & 1, threadIdx.x, featH, WinT, b_in, hb,
                     (const unsigned short*)nullptr, (const float*)nullptr,
                     (unsigned short*)nullptr, N_NODES, IN_DIM, HID,
                     smem, smem + 4096, smem + 12288);
    } else {
        scans_unit(bid - GEMM_TILES, threadIdx.x, cnt, bsum, offs, cursor,
                   (int*)(void*)smem);
    }
}

// ---------------- D3: layer-0 dual GEMM || CSR fill ----------------
__global__ __launch_bounds__(256, 4) void gemm1_fill_kernel(
    const unsigned short* __restrict__ hb,
    const unsigned short* __restrict__ WTs, const float* __restrict__ bs,
    unsigned short* __restrict__ fsb,
    const unsigned short* __restrict__ WTd, const float* __restrict__ bd,
    unsigned short* __restrict__ fdb,
    const int* __restrict__ src, const int* __restrict__ dst,
    int* __restrict__ cursor, int* __restrict__ csr_src) {
    __shared__ __align__(16) unsigned short smem[20480];
    int bid = blockIdx.x;
    if (bid < GEMM_TILES) {
        gemm_tile<1>(bid >> 1, bid & 1, threadIdx.x, hb, WTs, bs, fsb, WTd, bd, fdb,
                     N_NODES, HID, HID, smem, smem + 4096, smem + 12288);
    } else {
        int e = (bid - GEMM_TILES) * 256 + threadIdx.x;
        if (e < N_EDGES) {
            int sv = src[e];
            int p = atomicAdd(&cursor[dst[e] * NBKT + (sv >> 12)], 1);
            csr_src[p] = sv;
        }
    }
}

// ---------------- standalone dual GEMM (layers 1,2) ----------------
__global__ __launch_bounds__(256, 4) void gemm_kernel(
    const unsigned short* __restrict__ Ah,
    const unsigned short* __restrict__ BT1, const float* __restrict__ bias1,
    unsigned short* __restrict__ O1,
    const unsigned short* __restrict__ BT2, const float* __restrict__ bias2,
    unsigned short* __restrict__ O2) {
    __shared__ __align__(16) unsigned short smem[20480];
    gemm_tile<1>(blockIdx.x, blockIdx.y, threadIdx.x, Ah, BT1, bias1, O1,
                 BT2, bias2, O2, N_NODES, HID, HID, smem, smem + 4096, smem + 12288);
}

// ---------------- aggregation dispatch ----------------
__global__ __launch_bounds__(256) void agg_kernel(const unsigned short* __restrict__ fsb,
                                                  const unsigned short* __restrict__ fdb,
                                                  unsigned short* __restrict__ hb,
                                                  const int* __restrict__ offs,
                                                  const int* __restrict__ csr_src,
                                                  const float* __restrict__ attn_l) {
    agg_unit(blockIdx.x, threadIdx.x, fsb, fdb, hb, offs, csr_src, attn_l);
}

// ---------------- D9: fused pool + classifier (one block per graph, 8-row-parallel pool) ----------------
__global__ __launch_bounds__(256) void poolcls_kernel(
    const unsigned short* __restrict__ hb, const int* __restrict__ gid,
    const float* __restrict__ Wc1, const float* __restrict__ bc1,
    const float* __restrict__ Wc2, const float* __restrict__ bc2,
    const float* __restrict__ Wc3, const float* __restrict__ bc3,
    float* __restrict__ out) {
    __shared__ float part[8 * HID];   // 8 row-group partials
    __shared__ float xin[HID];
    __shared__ float x1[HID];
    __shared__ float x2[HID / 2];
    int g = blockIdx.x, t = threadIdx.x;

    // node range of graph g in sorted gid: [s0, e0)
    int lo = 0, hi = N_NODES;
    while (lo < hi) { int mid = (lo + hi) >> 1; if (gid[mid] < g) lo = mid + 1; else hi = mid; }
    int s0 = lo;
    hi = N_NODES;
    while (lo < hi) { int mid = (lo + hi) >> 1; if (gid[mid] < g + 1) lo = mid + 1; else hi = mid; }
    int e0 = lo;

    // pool: 8 row-groups x 32 lanes; lane handles 8 features via uint4; 2 rows in flight
    int r = t >> 5;            // 0..7
    int fb = (t & 31) * 8;     // feature base
    float a0[8], a1[8];
#pragma unroll
    for (int j = 0; j < 8; ++j) { a0[j] = 0.f; a1[j] = 0.f; }
    int n = s0 + r;
    for (; n + 8 < e0; n += 16) {
        uint4 u0 = *(const uint4*)(hb + (size_t)n * HID + fb);
        uint4 u1 = *(const uint4*)(hb + (size_t)(n + 8) * HID + fb);
        float f0[8], f1[8];
        unpack8(u0, f0); unpack8(u1, f1);
#pragma unroll
        for (int j = 0; j < 8; ++j) { a0[j] += f0[j]; a1[j] += f1[j]; }
    }
    if (n < e0) {
        uint4 u0 = *(const uint4*)(hb + (size_t)n * HID + fb);
        float f0[8];
        unpack8(u0, f0);
#pragma unroll
        for (int j = 0; j < 8; ++j) a0[j] += f0[j];
    }
#pragma unroll
    for (int j = 0; j < 8; ++j) part[r * HID + fb + j] = a0[j] + a1[j];
    __syncthreads();
    {
        float s = 0.f;
#pragma unroll
        for (int r2 = 0; r2 < 8; ++r2) s += part[r2 * HID + t];
        xin[t] = s;
    }
    __syncthreads();

    {
        float acc = bc1[t];
        for (int k = 0; k < HID; ++k) acc += xin[k] * Wc1[k * HID + t];
        x1[t] = fmaxf(acc, 0.f);
    }
    __syncthreads();
    if (t < HID / 2) {
        float acc = bc2[t];
        for (int k = 0; k < HID; ++k) acc += x1[k] * Wc2[k * (HID / 2) + t];
        x2[t] = fmaxf(acc, 0.f);
    }
    __syncthreads();
    if (t < OUT_DIM) {
        float acc = bc3[t];
        for (int k = 0; k < HID / 2; ++k) acc += x2[k] * Wc3[k * OUT_DIM + t];
        out[g * OUT_DIM + t] = acc;
    }
}

// ---------------- launch: 10 dispatches (memset + 9 kernels) ----------------
extern "C" void kernel_launch(void* const* d_in, const int* in_sizes, int n_in,
                              void* d_out, int out_size, void* d_ws, size_t ws_size,
                              hipStream_t stream) {
    const float* feature = (const float*)d_in[0];
    const float* W_in   = (const float*)d_in[1];
    const float* b_in   = (const float*)d_in[2];
    const float* W_src  = (const float*)d_in[3];
    const float* b_src  = (const float*)d_in[4];
    const float* W_dst  = (const float*)d_in[5];
    const float* b_dst  = (const float*)d_in[6];
    const float* attn   = (const float*)d_in[7];
    const float* Wc1    = (const float*)d_in[8];
    const float* bc1    = (const float*)d_in[9];
    const float* Wc2    = (const float*)d_in[10];
    const float* bc2    = (const float*)d_in[11];
    const float* Wc3    = (const float*)d_in[12];
    const float* bc3    = (const float*)d_in[13];
    const int* src     = (const int*)d_in[14];
    const int* dst     = (const int*)d_in[15];
    const int* gid     = (const int*)d_in[16];
    float* out = (float*)d_out;

    char* w = (char*)d_ws;
    auto alloc = [&](size_t bytes) -> void* {
        void* p = (void*)w;
        w += (bytes + 255) & ~(size_t)255;
        return p;
    };
    unsigned short* hb  = (unsigned short*)alloc((size_t)N_NODES * HID * 2);  // unified bf16 h
    unsigned short* fsb = (unsigned short*)alloc((size_t)N_NODES * HID * 2);
    unsigned short* fdb = (unsigned short*)alloc((size_t)N_NODES * HID * 2);
    int* cnt     = (int*)alloc((size_t)N_BINS * 4);        // 400000 -> 400128 rounded
    int* bsum    = (int*)alloc((size_t)N_CHUNK * 4);       // adjacent: one memset covers both
    int* offs    = (int*)alloc((size_t)(N_BINS + 4) * 4);
    int* cursor  = (int*)alloc((size_t)N_BINS * 4);
    int* csr_src = (int*)alloc((size_t)N_EDGES * 4);
    unsigned short* WinT = (unsigned short*)alloc((size_t)IN_DIM * HID * 2);
    unsigned short* WT   = (unsigned short*)alloc((size_t)6 * HID * HID * 2);
    unsigned short* featH = (unsigned short*)alloc((size_t)N_NODES * IN_DIM * 2);
    (void)alloc(4096);  // slack for clamped staging overreach

    // D0: zero cnt + bsum (contiguous region, one memset)
    size_t zlen = (size_t)((char*)offs - (char*)cnt);
    hipMemsetAsync(cnt, 0, zlen, stream);

    // D1: prep (feature cast + weight transposes) || edge-bin count (+chunk totals)
    hipLaunchKernelGGL(prep_count_kernel, dim3(PREP_BLOCKS + COUNT_BLOCKS), dim3(256), 0, stream,
                       feature, W_in, W_src, W_dst, featH, WinT, WT, src, dst, cnt, bsum);

    // D2: input-projection GEMM || wide scan (98 blocks)
    hipLaunchKernelGGL(gemm0_scan_kernel, dim3(GEMM_TILES + N_CHUNK), dim3(256), 0, stream,
                       featH, WinT, b_in, hb, cnt, bsum, offs, cursor);

    // D3: layer-0 dual GEMM || CSR fill
    hipLaunchKernelGGL(gemm1_fill_kernel, dim3(GEMM_TILES + COUNT_BLOCKS), dim3(256), 0, stream,
                       hb, WT, b_src, fsb, WT + 3 * 65536, b_dst, fdb,
                       src, dst, cursor, csr_src);

    // D4..D8: agg0, gemm_l1, agg1, gemm_l2, agg2
    for (int l = 0; l < LAYERS; ++l) {
        hipLaunchKernelGGL(agg_kernel, dim3(N_NODES / 8), dim3(256), 0, stream,
                           fsb, fdb, hb, offs, csr_src, attn + (size_t)l * HEADS * DH);
        if (l + 1 < LAYERS) {
            hipLaunchKernelGGL(gemm_kernel, dim3(313, 2), dim3(256), 0, stream,
                               hb, WT + (size_t)(l + 1) * 65536, b_src + (size_t)(l + 1) * HID, fsb,
                               WT + (size_t)(4 + l) * 65536, b_dst + (size_t)(l + 1) * HID, fdb);
        }
    }

    // D9: fused graph-sum-pool + classifier
    hipLaunchKernelGGL(poolcls_kernel, dim3(NUM_GRAPHS), dim3(256), 0, stream,
                       hb, gid, Wc1, bc1, Wc2, bc2, Wc3, bc3, out);
}

// Round 4
// 316.764 us; speedup vs baseline: 1.9969x; 1.9969x over previous
//
#include <hip/hip_runtime.h>
#include <hip/hip_bf16.h>
#include <math.h>

#define N_NODES 20000
#define N_EDGES 320000
#define IN_DIM 128
#define HID 256
#define HEADS 8
#define DH 32
#define LAYERS 3
#define NUM_GRAPHS 64
#define OUT_DIM 10
#define SLOPE 0.2f

// src-bucketed CSR: bucket = src >> 12 (4096 nodes = 2 MB of fsb per bucket)
#define NBKT 5
#define N_BINS (N_NODES * NBKT)      // 100000
#define N_BINS4 (N_BINS / 4)         // 25000

// scan chunks aligned to node boundaries: 1020 bins = 204 nodes * 5 buckets.
// Each chunk's extent is allocated with ONE atomicAdd on a global cursor, so
// offs is per-chunk-contiguous (covers every node's 5 bins) but NOT globally
// sorted -- nothing downstream needs the canonical order.
#define CHUNK_I4 255                 // int4s per chunk (1020 bins)
#define N_CHUNKS 99                  // ceil(100000 / 1020)

#define GEMM_TILES 626               // 313 m-tiles x 2 n-tiles
#define COUNT_BLOCKS 1250            // 320000 / 256

typedef __bf16 bf16x8 __attribute__((ext_vector_type(8)));
typedef float f32x4 __attribute__((ext_vector_type(4)));

static __device__ __forceinline__ unsigned short f2bfbits(float v) {
    __bf16 b = (__bf16)v;
    return __builtin_bit_cast(unsigned short, b);
}
// unpack 8 bf16 (in a uint4) -> 8 fp32, exact
static __device__ __forceinline__ void unpack8(uint4 u, float* f) {
    unsigned p0 = u.x, p1 = u.y, p2 = u.z, p3 = u.w;
    f[0] = __builtin_bit_cast(float, p0 << 16);
    f[1] = __builtin_bit_cast(float, p0 & 0xffff0000u);
    f[2] = __builtin_bit_cast(float, p1 << 16);
    f[3] = __builtin_bit_cast(float, p1 & 0xffff0000u);
    f[4] = __builtin_bit_cast(float, p2 << 16);
    f[5] = __builtin_bit_cast(float, p2 & 0xffff0000u);
    f[6] = __builtin_bit_cast(float, p3 << 16);
    f[7] = __builtin_bit_cast(float, p3 & 0xffff0000u);
}

// async 16B global->LDS (DMA, wave-uniform LDS base + lane*16)
typedef const __attribute__((address_space(1))) unsigned int* as1_u32p;
typedef __attribute__((address_space(3))) unsigned int* as3_u32p;
static __device__ __forceinline__ void async_cp16(const unsigned short* g, unsigned short* l) {
    __builtin_amdgcn_global_load_lds((as1_u32p)g, (as3_u32p)l, 16, 0, 0);
}

// ---------------- prep: feature cast, weight transpose/cast ----------------
#define CAST_N4 (N_NODES * IN_DIM / 4)                 // 640000
#define WTRANS_TOTAL (IN_DIM * HID + 6 * HID * HID)    // 425984
#define PREP_TOTAL (CAST_N4 + WTRANS_TOTAL)            // 1065984 = 4164 * 256
#define PREP_BLOCKS (PREP_TOTAL / 256)                 // 4164 (exact)

static __device__ void prep_item(int idx,
                                 const float* __restrict__ feat,
                                 const float* __restrict__ Win,
                                 const float* __restrict__ Wsrc,
                                 const float* __restrict__ Wdst,
                                 unsigned short* __restrict__ featH,
                                 unsigned short* __restrict__ WinT,
                                 unsigned short* __restrict__ WT) {
    if (idx < CAST_N4) {
        float4 v = ((const float4*)feat)[idx];
        ushort4 o;
        o.x = f2bfbits(v.x); o.y = f2bfbits(v.y);
        o.z = f2bfbits(v.z); o.w = f2bfbits(v.w);
        ((ushort4*)featH)[idx] = o;
    } else {
        int j = idx - CAST_N4;
        if (j < IN_DIM * HID) {
            int n = j / IN_DIM, k = j % IN_DIM;
            WinT[j] = f2bfbits(Win[k * HID + n]);
        } else {
            int r6 = j - IN_DIM * HID;
            int mat = r6 >> 16;
            int r = r6 & 65535;
            int n = r >> 8, k = r & 255;
            const float* base = (mat < 3) ? (Wsrc + (size_t)mat * 65536)
                                          : (Wdst + (size_t)(mat - 3) * 65536);
            WT[r6] = f2bfbits(base[k * 256 + n]);
        }
    }
}

// ---------------- wide scan: block u scans its 1020-bin chunk; base via one atomicAdd ----------------
static __device__ void scans_unit(int u, int t, const int* __restrict__ cnt,
                                  int* __restrict__ cglob, int* __restrict__ offs,
                                  int* __restrict__ cursor, int* si) {
    int idx4 = u * CHUNK_I4 + t;               // t in [0,256); active t < 255
    bool act = (t < CHUNK_I4) && (idx4 < N_BINS4);
    int4 x = make_int4(0, 0, 0, 0);
    if (act) x = ((const int4*)cnt)[idx4];
    int tsum = x.x + x.y + x.z + x.w;
    int v = tsum;
#pragma unroll
    for (int d = 1; d < 64; d <<= 1) {
        int w = __shfl_up(v, d, 64);
        if ((t & 63) >= d) v += w;
    }
    if ((t & 63) == 63) si[4 + (t >> 6)] = v;
    __syncthreads();
    if (t == 0) {
        int S = si[4] + si[5] + si[6] + si[7];
        si[0] = atomicAdd(cglob, S);           // 99 atomics total -- no contention
    }
    __syncthreads();
    int base = si[0];
    int wid = t >> 6;
    int waveoff = 0;
    if (wid > 0) waveoff += si[4];
    if (wid > 1) waveoff += si[5];
    if (wid > 2) waveoff += si[6];
    int ex = base + waveoff + (v - tsum);
    if (act) {
        int4 o;
        o.x = ex; o.y = ex + x.x; o.z = o.y + x.y; o.w = o.z + x.z;
        ((int4*)offs)[idx4] = o;
        ((int4*)cursor)[idx4] = o;
    }
}

// ---------------- MFMA GEMM tile: bf16 A, M64 x N128, BK=32 (proven code) ----------------
template <int DUAL>
static __device__ void gemm_tile(int mt, int nt, int t,
                                 const unsigned short* __restrict__ Ah,
                                 const unsigned short* __restrict__ BT1,
                                 const float* __restrict__ bias1,
                                 unsigned short* __restrict__ O1,
                                 const unsigned short* __restrict__ BT2,
                                 const float* __restrict__ bias2,
                                 unsigned short* __restrict__ O2,
                                 int M, int K, int N,
                                 unsigned short* AsP, unsigned short* Bs1P,
                                 unsigned short* Bs2P) {
    const int wv = t >> 6, lane = t & 63, quad = lane >> 4, l15 = lane & 15;
    const int m0 = mt * 64, n0 = nt * 128;

    const int sA = wv * 64 + lane;
    const int rA = sA >> 2, cA = (sA & 3) ^ ((rA >> 1) & 3);
    int gmA = m0 + rA; if (gmA >= M) gmA = M - 1;
    const size_t offA = (size_t)gmA * K + cA * 8;
    const int sB0 = wv * 64 + lane, sB1v = sB0 + 256;
    const int rB0 = sB0 >> 2, cB0 = (sB0 & 3) ^ ((rB0 >> 1) & 3);
    const int rB1 = sB1v >> 2, cB1 = (sB1v & 3) ^ ((rB1 >> 1) & 3);
    const size_t offB0 = (size_t)(n0 + rB0) * K + cB0 * 8;
    const size_t offB1 = (size_t)(n0 + rB1) * K + cB1 * 8;

    auto issue = [&](int buf, int k0) {
        async_cp16(Ah + offA + k0, AsP + buf * 2048 + wv * 512);
        async_cp16(BT1 + offB0 + k0, Bs1P + buf * 4096 + wv * 512);
        async_cp16(BT1 + offB1 + k0, Bs1P + buf * 4096 + 2048 + wv * 512);
        if (DUAL) {
            async_cp16(BT2 + offB0 + k0, Bs2P + buf * 4096 + wv * 512);
            async_cp16(BT2 + offB1 + k0, Bs2P + buf * 4096 + 2048 + wv * 512);
        }
    };

    const int mrow0 = (wv >> 1) * 32;
    const int ncb = (wv & 1) * 64;

    f32x4 zero = {0.f, 0.f, 0.f, 0.f};
    f32x4 acc1[2][4], acc2[2][4];
#pragma unroll
    for (int mi = 0; mi < 2; ++mi)
#pragma unroll
        for (int t4 = 0; t4 < 4; ++t4) { acc1[mi][t4] = zero; acc2[mi][t4] = zero; }

    issue(0, 0);
    int buf = 0;
    for (int k0 = 0; k0 < K; k0 += 32, buf ^= 1) {
        __syncthreads();
        if (k0 + 32 < K) issue(buf ^ 1, k0 + 32);

        bf16x8 aF[2];
#pragma unroll
        for (int mi = 0; mi < 2; ++mi) {
            int row = mrow0 + mi * 16 + l15;
            int aoff = row * 32 + ((quad ^ ((row >> 1) & 3)) << 3);
            aF[mi] = __builtin_bit_cast(bf16x8, *(const uint4*)(AsP + buf * 2048 + aoff));
        }
#pragma unroll
        for (int t4 = 0; t4 < 4; ++t4) {
            int brow = ncb + t4 * 16 + l15;
            int boff = brow * 32 + ((quad ^ ((brow >> 1) & 3)) << 3);
            bf16x8 b1 = __builtin_bit_cast(bf16x8, *(const uint4*)(Bs1P + buf * 4096 + boff));
#pragma unroll
            for (int mi = 0; mi < 2; ++mi)
                acc1[mi][t4] = __builtin_amdgcn_mfma_f32_16x16x32_bf16(aF[mi], b1, acc1[mi][t4], 0, 0, 0);
            if (DUAL) {
                bf16x8 b2 = __builtin_bit_cast(bf16x8, *(const uint4*)(Bs2P + buf * 4096 + boff));
#pragma unroll
                for (int mi = 0; mi < 2; ++mi)
                    acc2[mi][t4] = __builtin_amdgcn_mfma_f32_16x16x32_bf16(aF[mi], b2, acc2[mi][t4], 0, 0, 0);
            }
        }
    }

    float bia1[4], bia2[4];
#pragma unroll
    for (int t4 = 0; t4 < 4; ++t4) {
        bia1[t4] = bias1[n0 + ncb + t4 * 16 + l15];
        bia2[t4] = DUAL ? bias2[n0 + ncb + t4 * 16 + l15] : 0.f;
    }
#pragma unroll
    for (int mi = 0; mi < 2; ++mi) {
#pragma unroll
        for (int t4 = 0; t4 < 4; ++t4) {
            int gn = n0 + ncb + t4 * 16 + l15;
#pragma unroll
            for (int r = 0; r < 4; ++r) {
                int gm = m0 + mrow0 + mi * 16 + quad * 4 + r;
                if (gm < M) {
                    float v = acc1[mi][t4][r] + bia1[t4];
                    O1[(size_t)gm * N + gn] = f2bfbits(v);
                    if (DUAL) {
                        float v2 = acc2[mi][t4][r] + bia2[t4];
                        O2[(size_t)gm * N + gn] = f2bfbits(v2);
                    }
                }
            }
        }
    }
}

// ---------------- GATv2 aggregation (proven code; end now from offs+cnt) ----------------
static __device__ void agg_unit(int u, int t,
                                const unsigned short* __restrict__ fsb,
                                const unsigned short* __restrict__ fdb,
                                unsigned short* __restrict__ hb,
                                const int* __restrict__ offs,
                                const int* __restrict__ cnt,
                                const int* __restrict__ csr_src,
                                const float* __restrict__ attn_l) {
    int node = u * 8 + (t >> 5);
    if (node >= N_NODES) return;
    int l32 = t & 31;
    int dbase = l32 * 8;
    int abase = (l32 >> 2) * DH + (l32 & 3) * 8;

    float a[8];
#pragma unroll
    for (int j = 0; j < 8; ++j) a[j] = attn_l[abase + j];

    float fdv[8];
    unpack8(*(const uint4*)(fdb + (size_t)node * HID + dbase), fdv);

    float ssum0 = 0.f, ssum1 = 0.f;
    float acc0[8], acc1[8];
#pragma unroll
    for (int j = 0; j < 8; ++j) { acc0[j] = 0.f; acc1[j] = 0.f; }

    auto procE = [&](uint4 uu, float* acc, float& ssum) {
        float fsv[8];
        unpack8(uu, fsv);
        float p = 0.f;
#pragma unroll
        for (int j = 0; j < 8; ++j) {
            float e = fsv[j] + fdv[j];
            e = fmaxf(e, SLOPE * e);   // leakyrelu (slope<1)
            p += e * a[j];
        }
        p += __shfl_xor(p, 1, 64);
        p += __shfl_xor(p, 2, 64);
        float w = __expf(p);
        ssum += w;
#pragma unroll
        for (int j = 0; j < 8; ++j) acc[j] += w * fsv[j];
    };

    const unsigned short* fsl = fsb + dbase;
    int b0 = node * NBKT;
    int beg = offs[b0];
    int end = offs[b0 + NBKT - 1] + cnt[b0 + NBKT - 1];  // chunk-local contiguity
    int nfull = (end - beg) >> 2;
    const int limit = beg + nfull * 4;

    uint4 cu0, cu1, cu2, cu3;
    int ci0, ci1, ci2, ci3;
    int base = beg + 8;
    bool have = (nfull >= 1);
    bool haveN = (nfull >= 2);
    if (have) {
        int s0 = csr_src[beg], s1 = csr_src[beg + 1];
        int s2 = csr_src[beg + 2], s3 = csr_src[beg + 3];
        if (haveN) {
            ci0 = csr_src[beg + 4]; ci1 = csr_src[beg + 5];
            ci2 = csr_src[beg + 6]; ci3 = csr_src[beg + 7];
        }
        cu0 = *(const uint4*)(fsl + (size_t)s0 * HID);
        cu1 = *(const uint4*)(fsl + (size_t)s1 * HID);
        cu2 = *(const uint4*)(fsl + (size_t)s2 * HID);
        cu3 = *(const uint4*)(fsl + (size_t)s3 * HID);
    }
    while (have) {
        uint4 nu0, nu1, nu2, nu3;
        int ni0, ni1, ni2, ni3;
        if (haveN) {
            nu0 = *(const uint4*)(fsl + (size_t)ci0 * HID);
            nu1 = *(const uint4*)(fsl + (size_t)ci1 * HID);
            nu2 = *(const uint4*)(fsl + (size_t)ci2 * HID);
            nu3 = *(const uint4*)(fsl + (size_t)ci3 * HID);
        }
        bool haveNN = (base + 4 <= limit);
        if (haveNN) {
            ni0 = csr_src[base]; ni1 = csr_src[base + 1];
            ni2 = csr_src[base + 2]; ni3 = csr_src[base + 3];
        }
        base += 4;
        procE(cu0, acc0, ssum0);
        procE(cu1, acc1, ssum1);
        procE(cu2, acc0, ssum0);
        procE(cu3, acc1, ssum1);
        if (haveN) { cu0 = nu0; cu1 = nu1; cu2 = nu2; cu3 = nu3; }
        if (haveNN) { ci0 = ni0; ci1 = ni1; ci2 = ni2; ci3 = ni3; }
        have = haveN; haveN = haveNN;
    }
    for (int idx = limit; idx < end; ++idx) {
        int sv = csr_src[idx];
        procE(*(const uint4*)(fsl + (size_t)sv * HID), acc0, ssum0);
    }

    float ssum = ssum0 + ssum1;
    float acc[8];
#pragma unroll
    for (int j = 0; j < 8; ++j) acc[j] = acc0[j] + acc1[j];

    float inv = ssum > 0.f ? 1.f / ssum : 0.f;
    float hv[8];
    unpack8(*(const uint4*)(hb + (size_t)node * HID + dbase), hv);
    unsigned short ob[8];
#pragma unroll
    for (int j = 0; j < 8; ++j) {
        float o = fmaxf(acc[j] * inv + hv[j], 0.f);
        ob[j] = f2bfbits(o);
    }
    *(uint4*)(hb + (size_t)node * HID + dbase) = *(uint4*)ob;
}

// ---------------- D1: prep || count (cnt only -- no chunk-total atomics) ----------------
__global__ void prep_count_kernel(const float* __restrict__ feat,
                                  const float* __restrict__ Win,
                                  const float* __restrict__ Wsrc,
                                  const float* __restrict__ Wdst,
                                  unsigned short* __restrict__ featH,
                                  unsigned short* __restrict__ WinT,
                                  unsigned short* __restrict__ WT,
                                  const int* __restrict__ src,
                                  const int* __restrict__ dst,
                                  int* __restrict__ cnt) {
    int bid = blockIdx.x;
    if (bid < PREP_BLOCKS) {
        prep_item(bid * 256 + threadIdx.x, feat, Win, Wsrc, Wdst, featH, WinT, WT);
    } else {
        int e = (bid - PREP_BLOCKS) * 256 + threadIdx.x;
        if (e < N_EDGES) atomicAdd(&cnt[dst[e] * NBKT + (src[e] >> 12)], 1);
    }
}

// ---------------- D2: input-projection GEMM || wide chunk scan (99 blocks) ----------------
__global__ __launch_bounds__(256, 4) void gemm0_scan_kernel(
    const unsigned short* __restrict__ featH, const unsigned short* __restrict__ WinT,
    const float* __restrict__ b_in, unsigned short* __restrict__ hb,
    const int* __restrict__ cnt, int* __restrict__ cglob,
    int* __restrict__ offs, int* __restrict__ cursor) {
    __shared__ __align__(16) unsigned short smem[20480];
    int bid = blockIdx.x;
    if (bid < GEMM_TILES) {
        gemm_tile<0>(bid >> 1, bid & 1, threadIdx.x, featH, WinT, b_in, hb,
                     (const unsigned short*)nullptr, (const float*)nullptr,
                     (unsigned short*)nullptr, N_NODES, IN_DIM, HID,
                     smem, smem + 4096, smem + 12288);
    } else {
        scans_unit(bid - GEMM_TILES, threadIdx.x, cnt, cglob, offs, cursor,
                   (int*)(void*)smem);
    }
}

// ---------------- D3: layer-0 dual GEMM || CSR fill ----------------
__global__ __launch_bounds__(256, 4) void gemm1_fill_kernel(
    const unsigned short* __restrict__ hb,
    const unsigned short* __restrict__ WTs, const float* __restrict__ bs,
    unsigned short* __restrict__ fsb,
    const unsigned short* __restrict__ WTd, const float* __restrict__ bd,
    unsigned short* __restrict__ fdb,
    const int* __restrict__ src, const int* __restrict__ dst,
    int* __restrict__ cursor, int* __restrict__ csr_src) {
    __shared__ __align__(16) unsigned short smem[20480];
    int bid = blockIdx.x;
    if (bid < GEMM_TILES) {
        gemm_tile<1>(bid >> 1, bid & 1, threadIdx.x, hb, WTs, bs, fsb, WTd, bd, fdb,
                     N_NODES, HID, HID, smem, smem + 4096, smem + 12288);
    } else {
        int e = (bid - GEMM_TILES) * 256 + threadIdx.x;
        if (e < N_EDGES) {
            int sv = src[e];
            int p = atomicAdd(&cursor[dst[e] * NBKT + (sv >> 12)], 1);
            csr_src[p] = sv;
        }
    }
}

// ---------------- standalone dual GEMM (layers 1,2) ----------------
__global__ __launch_bounds__(256, 4) void gemm_kernel(
    const unsigned short* __restrict__ Ah,
    const unsigned short* __restrict__ BT1, const float* __restrict__ bias1,
    unsigned short* __restrict__ O1,
    const unsigned short* __restrict__ BT2, const float* __restrict__ bias2,
    unsigned short* __restrict__ O2) {
    __shared__ __align__(16) unsigned short smem[20480];
    gemm_tile<1>(blockIdx.x, blockIdx.y, threadIdx.x, Ah, BT1, bias1, O1,
                 BT2, bias2, O2, N_NODES, HID, HID, smem, smem + 4096, smem + 12288);
}

// ---------------- aggregation dispatch ----------------
__global__ __launch_bounds__(256) void agg_kernel(const unsigned short* __restrict__ fsb,
                                                  const unsigned short* __restrict__ fdb,
                                                  unsigned short* __restrict__ hb,
                                                  const int* __restrict__ offs,
                                                  const int* __restrict__ cnt,
                                                  const int* __restrict__ csr_src,
                                                  const float* __restrict__ attn_l) {
    agg_unit(blockIdx.x, threadIdx.x, fsb, fdb, hb, offs, cnt, csr_src, attn_l);
}

// ---------------- D9: fused pool + classifier (one block per graph, 8-row-parallel pool) ----------------
__global__ __launch_bounds__(256) void poolcls_kernel(
    const unsigned short* __restrict__ hb, const int* __restrict__ gid,
    const float* __restrict__ Wc1, const float* __restrict__ bc1,
    const float* __restrict__ Wc2, const float* __restrict__ bc2,
    const float* __restrict__ Wc3, const float* __restrict__ bc3,
    float* __restrict__ out) {
    __shared__ float part[8 * HID];   // 8 row-group partials
    __shared__ float xin[HID];
    __shared__ float x1[HID];
    __shared__ float x2[HID / 2];
    int g = blockIdx.x, t = threadIdx.x;

    // node range of graph g in sorted gid: [s0, e0)
    int lo = 0, hi = N_NODES;
    while (lo < hi) { int mid = (lo + hi) >> 1; if (gid[mid] < g) lo = mid + 1; else hi = mid; }
    int s0 = lo;
    hi = N_NODES;
    while (lo < hi) { int mid = (lo + hi) >> 1; if (gid[mid] < g + 1) lo = mid + 1; else hi = mid; }
    int e0 = lo;

    // pool: 8 row-groups x 32 lanes; lane handles 8 features via uint4; 2 rows in flight
    int r = t >> 5;            // 0..7
    int fb = (t & 31) * 8;     // feature base
    float a0[8], a1[8];
#pragma unroll
    for (int j = 0; j < 8; ++j) { a0[j] = 0.f; a1[j] = 0.f; }
    int n = s0 + r;
    for (; n + 8 < e0; n += 16) {
        uint4 u0 = *(const uint4*)(hb + (size_t)n * HID + fb);
        uint4 u1 = *(const uint4*)(hb + (size_t)(n + 8) * HID + fb);
        float f0[8], f1[8];
        unpack8(u0, f0); unpack8(u1, f1);
#pragma unroll
        for (int j = 0; j < 8; ++j) { a0[j] += f0[j]; a1[j] += f1[j]; }
    }
    if (n < e0) {
        uint4 u0 = *(const uint4*)(hb + (size_t)n * HID + fb);
        float f0[8];
        unpack8(u0, f0);
#pragma unroll
        for (int j = 0; j < 8; ++j) a0[j] += f0[j];
    }
#pragma unroll
    for (int j = 0; j < 8; ++j) part[r * HID + fb + j] = a0[j] + a1[j];
    __syncthreads();
    {
        float s = 0.f;
#pragma unroll
        for (int r2 = 0; r2 < 8; ++r2) s += part[r2 * HID + t];
        xin[t] = s;
    }
    __syncthreads();

    {
        float acc = bc1[t];
        for (int k = 0; k < HID; ++k) acc += xin[k] * Wc1[k * HID + t];
        x1[t] = fmaxf(acc, 0.f);
    }
    __syncthreads();
    if (t < HID / 2) {
        float acc = bc2[t];
        for (int k = 0; k < HID; ++k) acc += x1[k] * Wc2[k * (HID / 2) + t];
        x2[t] = fmaxf(acc, 0.f);
    }
    __syncthreads();
    if (t < OUT_DIM) {
        float acc = bc3[t];
        for (int k = 0; k < HID / 2; ++k) acc += x2[k] * Wc3[k * OUT_DIM + t];
        out[g * OUT_DIM + t] = acc;
    }
}

// ---------------- launch: 10 dispatches (memset + 9 kernels) ----------------
extern "C" void kernel_launch(void* const* d_in, const int* in_sizes, int n_in,
                              void* d_out, int out_size, void* d_ws, size_t ws_size,
                              hipStream_t stream) {
    const float* feature = (const float*)d_in[0];
    const float* W_in   = (const float*)d_in[1];
    const float* b_in   = (const float*)d_in[2];
    const float* W_src  = (const float*)d_in[3];
    const float* b_src  = (const float*)d_in[4];
    const float* W_dst  = (const float*)d_in[5];
    const float* b_dst  = (const float*)d_in[6];
    const float* attn   = (const float*)d_in[7];
    const float* Wc1    = (const float*)d_in[8];
    const float* bc1    = (const float*)d_in[9];
    const float* Wc2    = (const float*)d_in[10];
    const float* bc2    = (const float*)d_in[11];
    const float* Wc3    = (const float*)d_in[12];
    const float* bc3    = (const float*)d_in[13];
    const int* src     = (const int*)d_in[14];
    const int* dst     = (const int*)d_in[15];
    const int* gid     = (const int*)d_in[16];
    float* out = (float*)d_out;

    char* w = (char*)d_ws;
    auto alloc = [&](size_t bytes) -> void* {
        void* p = (void*)w;
        w += (bytes + 255) & ~(size_t)255;
        return p;
    };
    unsigned short* hb  = (unsigned short*)alloc((size_t)N_NODES * HID * 2);  // unified bf16 h
    unsigned short* fsb = (unsigned short*)alloc((size_t)N_NODES * HID * 2);
    unsigned short* fdb = (unsigned short*)alloc((size_t)N_NODES * HID * 2);
    int* cnt     = (int*)alloc((size_t)N_BINS * 4);   // cnt + cglob zeroed by one memset
    int* cglob   = (int*)alloc(4);
    int* offs    = (int*)alloc((size_t)(N_BINS + 4) * 4);
    int* cursor  = (int*)alloc((size_t)N_BINS * 4);
    int* csr_src = (int*)alloc((size_t)N_EDGES * 4);
    unsigned short* WinT = (unsigned short*)alloc((size_t)IN_DIM * HID * 2);
    unsigned short* WT   = (unsigned short*)alloc((size_t)6 * HID * HID * 2);
    unsigned short* featH = (unsigned short*)alloc((size_t)N_NODES * IN_DIM * 2);
    (void)alloc(4096);  // slack for clamped staging overreach

    // D0: zero cnt + cglob (contiguous region, one memset)
    size_t zlen = (size_t)((char*)offs - (char*)cnt);
    hipMemsetAsync(cnt, 0, zlen, stream);

    // D1: prep (feature cast + weight transposes) || edge-bin count
    hipLaunchKernelGGL(prep_count_kernel, dim3(PREP_BLOCKS + COUNT_BLOCKS), dim3(256), 0, stream,
                       feature, W_in, W_src, W_dst, featH, WinT, WT, src, dst, cnt);

    // D2: input-projection GEMM || wide chunk scan (99 blocks, 1 atomic each)
    hipLaunchKernelGGL(gemm0_scan_kernel, dim3(GEMM_TILES + N_CHUNKS), dim3(256), 0, stream,
                       featH, WinT, b_in, hb, cnt, cglob, offs, cursor);

    // D3: layer-0 dual GEMM || CSR fill
    hipLaunchKernelGGL(gemm1_fill_kernel, dim3(GEMM_TILES + COUNT_BLOCKS), dim3(256), 0, stream,
                       hb, WT, b_src, fsb, WT + 3 * 65536, b_dst, fdb,
                       src, dst, cursor, csr_src);

    // D4..D8: agg0, gemm_l1, agg1, gemm_l2, agg2
    for (int l = 0; l < LAYERS; ++l) {
        hipLaunchKernelGGL(agg_kernel, dim3(N_NODES / 8), dim3(256), 0, stream,
                           fsb, fdb, hb, offs, cnt, csr_src, attn + (size_t)l * HEADS * DH);
        if (l + 1 < LAYERS) {
            hipLaunchKernelGGL(gemm_kernel, dim3(313, 2), dim3(256), 0, stream,
                               hb, WT + (size_t)(l + 1) * 65536, b_src + (size_t)(l + 1) * HID, fsb,
                               WT + (size_t)(4 + l) * 65536, b_dst + (size_t)(l + 1) * HID, fdb);
        }
    }

    // D9: fused graph-sum-pool + classifier
    hipLaunchKernelGGL(poolcls_kernel, dim3(NUM_GRAPHS), dim3(256), 0, stream,
                       hb, gid, Wc1, bc1, Wc2, bc2, Wc3, bc3, out);
}

// Round 5
// 316.208 us; speedup vs baseline: 2.0004x; 1.0018x over previous
//
#include <hip/hip_runtime.h>
#include <hip/hip_bf16.h>
#include <math.h>

#define N_NODES 20000
#define N_EDGES 320000
#define IN_DIM 128
#define HID 256
#define HEADS 8
#define DH 32
#define LAYERS 3
#define NUM_GRAPHS 64
#define OUT_DIM 10
#define SLOPE 0.2f

// src-bucketed CSR: bucket = src >> 12 (4096 nodes = 2 MB of fsb per bucket)
#define NBKT 5
#define N_BINS (N_NODES * NBKT)      // 100000
#define N_BINS4 (N_BINS / 4)         // 25000

// scan chunks aligned to node boundaries: 1020 bins = 204 nodes * 5 buckets.
#define CHUNK_I4 255                 // int4s per chunk (1020 bins)
#define N_CHUNKS 99                  // ceil(100000 / 1020)

#define GEMM_TILES 626               // 313 m-tiles x 2 n-tiles
#define COUNT_BLOCKS 1250            // 320000 / 256

typedef __bf16 bf16x8 __attribute__((ext_vector_type(8)));
typedef float f32x4 __attribute__((ext_vector_type(4)));

static __device__ __forceinline__ unsigned short f2bfbits(float v) {
    __bf16 b = (__bf16)v;
    return __builtin_bit_cast(unsigned short, b);
}
// unpack 8 bf16 (in a uint4) -> 8 fp32, exact
static __device__ __forceinline__ void unpack8(uint4 u, float* f) {
    unsigned p0 = u.x, p1 = u.y, p2 = u.z, p3 = u.w;
    f[0] = __builtin_bit_cast(float, p0 << 16);
    f[1] = __builtin_bit_cast(float, p0 & 0xffff0000u);
    f[2] = __builtin_bit_cast(float, p1 << 16);
    f[3] = __builtin_bit_cast(float, p1 & 0xffff0000u);
    f[4] = __builtin_bit_cast(float, p2 << 16);
    f[5] = __builtin_bit_cast(float, p2 & 0xffff0000u);
    f[6] = __builtin_bit_cast(float, p3 << 16);
    f[7] = __builtin_bit_cast(float, p3 & 0xffff0000u);
}

// async 16B global->LDS (DMA, wave-uniform LDS base + lane*16)
typedef const __attribute__((address_space(1))) unsigned int* as1_u32p;
typedef __attribute__((address_space(3))) unsigned int* as3_u32p;
static __device__ __forceinline__ void async_cp16(const unsigned short* g, unsigned short* l) {
    __builtin_amdgcn_global_load_lds((as1_u32p)g, (as3_u32p)l, 16, 0, 0);
}

// ---------------- prep: feature cast, weight transpose/cast ----------------
#define CAST_N4 (N_NODES * IN_DIM / 4)                 // 640000
#define WTRANS_TOTAL (IN_DIM * HID + 6 * HID * HID)    // 425984
#define PREP_TOTAL (CAST_N4 + WTRANS_TOTAL)            // 1065984 = 4164 * 256
#define PREP_BLOCKS (PREP_TOTAL / 256)                 // 4164 (exact)

static __device__ void prep_item(int idx,
                                 const float* __restrict__ feat,
                                 const float* __restrict__ Win,
                                 const float* __restrict__ Wsrc,
                                 const float* __restrict__ Wdst,
                                 unsigned short* __restrict__ featH,
                                 unsigned short* __restrict__ WinT,
                                 unsigned short* __restrict__ WT) {
    if (idx < CAST_N4) {
        float4 v = ((const float4*)feat)[idx];
        ushort4 o;
        o.x = f2bfbits(v.x); o.y = f2bfbits(v.y);
        o.z = f2bfbits(v.z); o.w = f2bfbits(v.w);
        ((ushort4*)featH)[idx] = o;
    } else {
        int j = idx - CAST_N4;
        if (j < IN_DIM * HID) {
            int n = j / IN_DIM, k = j % IN_DIM;
            WinT[j] = f2bfbits(Win[k * HID + n]);
        } else {
            int r6 = j - IN_DIM * HID;
            int mat = r6 >> 16;
            int r = r6 & 65535;
            int n = r >> 8, k = r & 255;
            const float* base = (mat < 3) ? (Wsrc + (size_t)mat * 65536)
                                          : (Wdst + (size_t)(mat - 3) * 65536);
            WT[r6] = f2bfbits(base[k * 256 + n]);
        }
    }
}

// ---------------- wide scan: block u scans its 1020-bin chunk; base via one atomicAdd ----------------
static __device__ void scans_unit(int u, int t, const int* __restrict__ cnt,
                                  int* __restrict__ cglob, int* __restrict__ offs,
                                  int* __restrict__ cursor, int* si) {
    int idx4 = u * CHUNK_I4 + t;               // t in [0,256); active t < 255
    bool act = (t < CHUNK_I4) && (idx4 < N_BINS4);
    int4 x = make_int4(0, 0, 0, 0);
    if (act) x = ((const int4*)cnt)[idx4];
    int tsum = x.x + x.y + x.z + x.w;
    int v = tsum;
#pragma unroll
    for (int d = 1; d < 64; d <<= 1) {
        int w = __shfl_up(v, d, 64);
        if ((t & 63) >= d) v += w;
    }
    if ((t & 63) == 63) si[4 + (t >> 6)] = v;
    __syncthreads();
    if (t == 0) {
        int S = si[4] + si[5] + si[6] + si[7];
        si[0] = atomicAdd(cglob, S);           // 99 atomics total -- no contention
    }
    __syncthreads();
    int base = si[0];
    int wid = t >> 6;
    int waveoff = 0;
    if (wid > 0) waveoff += si[4];
    if (wid > 1) waveoff += si[5];
    if (wid > 2) waveoff += si[6];
    int ex = base + waveoff + (v - tsum);
    if (act) {
        int4 o;
        o.x = ex; o.y = ex + x.x; o.z = o.y + x.y; o.w = o.z + x.z;
        ((int4*)offs)[idx4] = o;
        ((int4*)cursor)[idx4] = o;
    }
}

// ---------------- MFMA GEMM tile: bf16 A, M64 x N128, BK=32 ----------------
// Change vs proven r17 structure: the FULL A-tile (64 x K) is prefetched into
// LDS up front (one ~900cy HBM wait total) instead of per-K-step double-buffer.
// __syncthreads drains vmcnt(0), so per-step A-from-HBM stalled every step by
// (A_lat - compute) ~ 500cy; B is L2-resident (weights) and stays dbuf'd.
// AsP: (K/32) chunks of 2048 elems; fragment swizzle per chunk unchanged.
template <int DUAL>
static __device__ void gemm_tile(int mt, int nt, int t,
                                 const unsigned short* __restrict__ Ah,
                                 const unsigned short* __restrict__ BT1,
                                 const float* __restrict__ bias1,
                                 unsigned short* __restrict__ O1,
                                 const unsigned short* __restrict__ BT2,
                                 const float* __restrict__ bias2,
                                 unsigned short* __restrict__ O2,
                                 int M, int K, int N,
                                 unsigned short* AsP, unsigned short* Bs1P,
                                 unsigned short* Bs2P) {
    const int wv = t >> 6, lane = t & 63, quad = lane >> 4, l15 = lane & 15;
    const int m0 = mt * 64, n0 = nt * 128;

    const int sA = wv * 64 + lane;
    const int rA = sA >> 2, cA = (sA & 3) ^ ((rA >> 1) & 3);
    int gmA = m0 + rA; if (gmA >= M) gmA = M - 1;
    const size_t offA = (size_t)gmA * K + cA * 8;
    const int sB0 = wv * 64 + lane, sB1v = sB0 + 256;
    const int rB0 = sB0 >> 2, cB0 = (sB0 & 3) ^ ((rB0 >> 1) & 3);
    const int rB1 = sB1v >> 2, cB1 = (sB1v & 3) ^ ((rB1 >> 1) & 3);
    const size_t offB0 = (size_t)(n0 + rB0) * K + cB0 * 8;
    const size_t offB1 = (size_t)(n0 + rB1) * K + cB1 * 8;

    const int nk = K >> 5;                    // 4 (K=128) or 8 (K=256)
    for (int c = 0; c < nk; ++c)              // full-A prefetch, all chunks in flight
        async_cp16(Ah + offA + c * 32, AsP + c * 2048 + wv * 512);

    auto issueB = [&](int buf, int k0) {
        async_cp16(BT1 + offB0 + k0, Bs1P + buf * 4096 + wv * 512);
        async_cp16(BT1 + offB1 + k0, Bs1P + buf * 4096 + 2048 + wv * 512);
        if (DUAL) {
            async_cp16(BT2 + offB0 + k0, Bs2P + buf * 4096 + wv * 512);
            async_cp16(BT2 + offB1 + k0, Bs2P + buf * 4096 + 2048 + wv * 512);
        }
    };

    const int mrow0 = (wv >> 1) * 32;
    const int ncb = (wv & 1) * 64;

    f32x4 zero = {0.f, 0.f, 0.f, 0.f};
    f32x4 acc1[2][4], acc2[2][4];
#pragma unroll
    for (int mi = 0; mi < 2; ++mi)
#pragma unroll
        for (int t4 = 0; t4 < 4; ++t4) { acc1[mi][t4] = zero; acc2[mi][t4] = zero; }

    issueB(0, 0);
    int buf = 0;
    for (int k0 = 0; k0 < K; k0 += 32, buf ^= 1) {
        __syncthreads();
        if (k0 + 32 < K) issueB(buf ^ 1, k0 + 32);
        const unsigned short* Ak = AsP + (k0 >> 5) * 2048;

        bf16x8 aF[2];
#pragma unroll
        for (int mi = 0; mi < 2; ++mi) {
            int row = mrow0 + mi * 16 + l15;
            int aoff = row * 32 + ((quad ^ ((row >> 1) & 3)) << 3);
            aF[mi] = __builtin_bit_cast(bf16x8, *(const uint4*)(Ak + aoff));
        }
#pragma unroll
        for (int t4 = 0; t4 < 4; ++t4) {
            int brow = ncb + t4 * 16 + l15;
            int boff = brow * 32 + ((quad ^ ((brow >> 1) & 3)) << 3);
            bf16x8 b1 = __builtin_bit_cast(bf16x8, *(const uint4*)(Bs1P + buf * 4096 + boff));
#pragma unroll
            for (int mi = 0; mi < 2; ++mi)
                acc1[mi][t4] = __builtin_amdgcn_mfma_f32_16x16x32_bf16(aF[mi], b1, acc1[mi][t4], 0, 0, 0);
            if (DUAL) {
                bf16x8 b2 = __builtin_bit_cast(bf16x8, *(const uint4*)(Bs2P + buf * 4096 + boff));
#pragma unroll
                for (int mi = 0; mi < 2; ++mi)
                    acc2[mi][t4] = __builtin_amdgcn_mfma_f32_16x16x32_bf16(aF[mi], b2, acc2[mi][t4], 0, 0, 0);
            }
        }
    }

    float bia1[4], bia2[4];
#pragma unroll
    for (int t4 = 0; t4 < 4; ++t4) {
        bia1[t4] = bias1[n0 + ncb + t4 * 16 + l15];
        bia2[t4] = DUAL ? bias2[n0 + ncb + t4 * 16 + l15] : 0.f;
    }
#pragma unroll
    for (int mi = 0; mi < 2; ++mi) {
#pragma unroll
        for (int t4 = 0; t4 < 4; ++t4) {
            int gn = n0 + ncb + t4 * 16 + l15;
#pragma unroll
            for (int r = 0; r < 4; ++r) {
                int gm = m0 + mrow0 + mi * 16 + quad * 4 + r;
                if (gm < M) {
                    float v = acc1[mi][t4][r] + bia1[t4];
                    O1[(size_t)gm * N + gn] = f2bfbits(v);
                    if (DUAL) {
                        float v2 = acc2[mi][t4][r] + bia2[t4];
                        O2[(size_t)gm * N + gn] = f2bfbits(v2);
                    }
                }
            }
        }
    }
}

// ---------------- GATv2 aggregation (proven code; end from offs+cnt) ----------------
static __device__ void agg_unit(int u, int t,
                                const unsigned short* __restrict__ fsb,
                                const unsigned short* __restrict__ fdb,
                                unsigned short* __restrict__ hb,
                                const int* __restrict__ offs,
                                const int* __restrict__ cnt,
                                const int* __restrict__ csr_src,
                                const float* __restrict__ attn_l) {
    int node = u * 8 + (t >> 5);
    if (node >= N_NODES) return;
    int l32 = t & 31;
    int dbase = l32 * 8;
    int abase = (l32 >> 2) * DH + (l32 & 3) * 8;

    float a[8];
#pragma unroll
    for (int j = 0; j < 8; ++j) a[j] = attn_l[abase + j];

    float fdv[8];
    unpack8(*(const uint4*)(fdb + (size_t)node * HID + dbase), fdv);

    float ssum0 = 0.f, ssum1 = 0.f;
    float acc0[8], acc1[8];
#pragma unroll
    for (int j = 0; j < 8; ++j) { acc0[j] = 0.f; acc1[j] = 0.f; }

    auto procE = [&](uint4 uu, float* acc, float& ssum) {
        float fsv[8];
        unpack8(uu, fsv);
        float p = 0.f;
#pragma unroll
        for (int j = 0; j < 8; ++j) {
            float e = fsv[j] + fdv[j];
            e = fmaxf(e, SLOPE * e);   // leakyrelu (slope<1)
            p += e * a[j];
        }
        p += __shfl_xor(p, 1, 64);
        p += __shfl_xor(p, 2, 64);
        float w = __expf(p);
        ssum += w;
#pragma unroll
        for (int j = 0; j < 8; ++j) acc[j] += w * fsv[j];
    };

    const unsigned short* fsl = fsb + dbase;
    int b0 = node * NBKT;
    int beg = offs[b0];
    int end = offs[b0 + NBKT - 1] + cnt[b0 + NBKT - 1];  // chunk-local contiguity
    int nfull = (end - beg) >> 2;
    const int limit = beg + nfull * 4;

    uint4 cu0, cu1, cu2, cu3;
    int ci0, ci1, ci2, ci3;
    int base = beg + 8;
    bool have = (nfull >= 1);
    bool haveN = (nfull >= 2);
    if (have) {
        int s0 = csr_src[beg], s1 = csr_src[beg + 1];
        int s2 = csr_src[beg + 2], s3 = csr_src[beg + 3];
        if (haveN) {
            ci0 = csr_src[beg + 4]; ci1 = csr_src[beg + 5];
            ci2 = csr_src[beg + 6]; ci3 = csr_src[beg + 7];
        }
        cu0 = *(const uint4*)(fsl + (size_t)s0 * HID);
        cu1 = *(const uint4*)(fsl + (size_t)s1 * HID);
        cu2 = *(const uint4*)(fsl + (size_t)s2 * HID);
        cu3 = *(const uint4*)(fsl + (size_t)s3 * HID);
    }
    while (have) {
        uint4 nu0, nu1, nu2, nu3;
        int ni0, ni1, ni2, ni3;
        if (haveN) {
            nu0 = *(const uint4*)(fsl + (size_t)ci0 * HID);
            nu1 = *(const uint4*)(fsl + (size_t)ci1 * HID);
            nu2 = *(const uint4*)(fsl + (size_t)ci2 * HID);
            nu3 = *(const uint4*)(fsl + (size_t)ci3 * HID);
        }
        bool haveNN = (base + 4 <= limit);
        if (haveNN) {
            ni0 = csr_src[base]; ni1 = csr_src[base + 1];
            ni2 = csr_src[base + 2]; ni3 = csr_src[base + 3];
        }
        base += 4;
        procE(cu0, acc0, ssum0);
        procE(cu1, acc1, ssum1);
        procE(cu2, acc0, ssum0);
        procE(cu3, acc1, ssum1);
        if (haveN) { cu0 = nu0; cu1 = nu1; cu2 = nu2; cu3 = nu3; }
        if (haveNN) { ci0 = ni0; ci1 = ni1; ci2 = ni2; ci3 = ni3; }
        have = haveN; haveN = haveNN;
    }
    for (int idx = limit; idx < end; ++idx) {
        int sv = csr_src[idx];
        procE(*(const uint4*)(fsl + (size_t)sv * HID), acc0, ssum0);
    }

    float ssum = ssum0 + ssum1;
    float acc[8];
#pragma unroll
    for (int j = 0; j < 8; ++j) acc[j] = acc0[j] + acc1[j];

    float inv = ssum > 0.f ? 1.f / ssum : 0.f;
    float hv[8];
    unpack8(*(const uint4*)(hb + (size_t)node * HID + dbase), hv);
    unsigned short ob[8];
#pragma unroll
    for (int j = 0; j < 8; ++j) {
        float o = fmaxf(acc[j] * inv + hv[j], 0.f);
        ob[j] = f2bfbits(o);
    }
    *(uint4*)(hb + (size_t)node * HID + dbase) = *(uint4*)ob;
}

// ---------------- D1: prep || count ----------------
__global__ void prep_count_kernel(const float* __restrict__ feat,
                                  const float* __restrict__ Win,
                                  const float* __restrict__ Wsrc,
                                  const float* __restrict__ Wdst,
                                  unsigned short* __restrict__ featH,
                                  unsigned short* __restrict__ WinT,
                                  unsigned short* __restrict__ WT,
                                  const int* __restrict__ src,
                                  const int* __restrict__ dst,
                                  int* __restrict__ cnt) {
    int bid = blockIdx.x;
    if (bid < PREP_BLOCKS) {
        prep_item(bid * 256 + threadIdx.x, feat, Win, Wsrc, Wdst, featH, WinT, WT);
    } else {
        int e = (bid - PREP_BLOCKS) * 256 + threadIdx.x;
        if (e < N_EDGES) atomicAdd(&cnt[dst[e] * NBKT + (src[e] >> 12)], 1);
    }
}

// ---------------- D2: input-projection GEMM || wide chunk scan ----------------
// DUAL=0, K=128: As = 4 chunks (8192) + Bs1 dbuf (8192) = 32 KB LDS
__global__ __launch_bounds__(256, 4) void gemm0_scan_kernel(
    const unsigned short* __restrict__ featH, const unsigned short* __restrict__ WinT,
    const float* __restrict__ b_in, unsigned short* __restrict__ hb,
    const int* __restrict__ cnt, int* __restrict__ cglob,
    int* __restrict__ offs, int* __restrict__ cursor) {
    __shared__ __align__(16) unsigned short smem[16384];
    int bid = blockIdx.x;
    if (bid < GEMM_TILES) {
        gemm_tile<0>(bid >> 1, bid & 1, threadIdx.x, featH, WinT, b_in, hb,
                     (const unsigned short*)nullptr, (const float*)nullptr,
                     (unsigned short*)nullptr, N_NODES, IN_DIM, HID,
                     smem, smem + 8192, smem);
    } else {
        scans_unit(bid - GEMM_TILES, threadIdx.x, cnt, cglob, offs, cursor,
                   (int*)(void*)smem);
    }
}

// ---------------- D3: layer-0 dual GEMM || CSR fill ----------------
// DUAL=1, K=256: As = 8 chunks (16384) + Bs1 (8192) + Bs2 (8192) = 64 KB LDS
__global__ __launch_bounds__(256, 2) void gemm1_fill_kernel(
    const unsigned short* __restrict__ hb,
    const unsigned short* __restrict__ WTs, const float* __restrict__ bs,
    unsigned short* __restrict__ fsb,
    const unsigned short* __restrict__ WTd, const float* __restrict__ bd,
    unsigned short* __restrict__ fdb,
    const int* __restrict__ src, const int* __restrict__ dst,
    int* __restrict__ cursor, int* __restrict__ csr_src) {
    __shared__ __align__(16) unsigned short smem[32768];
    int bid = blockIdx.x;
    if (bid < GEMM_TILES) {
        gemm_tile<1>(bid >> 1, bid & 1, threadIdx.x, hb, WTs, bs, fsb, WTd, bd, fdb,
                     N_NODES, HID, HID, smem, smem + 16384, smem + 24576);
    } else {
        int e = (bid - GEMM_TILES) * 256 + threadIdx.x;
        if (e < N_EDGES) {
            int sv = src[e];
            int p = atomicAdd(&cursor[dst[e] * NBKT + (sv >> 12)], 1);
            csr_src[p] = sv;
        }
    }
}

// ---------------- standalone dual GEMM (layers 1,2) ----------------
__global__ __launch_bounds__(256, 2) void gemm_kernel(
    const unsigned short* __restrict__ Ah,
    const unsigned short* __restrict__ BT1, const float* __restrict__ bias1,
    unsigned short* __restrict__ O1,
    const unsigned short* __restrict__ BT2, const float* __restrict__ bias2,
    unsigned short* __restrict__ O2) {
    __shared__ __align__(16) unsigned short smem[32768];
    gemm_tile<1>(blockIdx.x, blockIdx.y, threadIdx.x, Ah, BT1, bias1, O1,
                 BT2, bias2, O2, N_NODES, HID, HID, smem, smem + 16384, smem + 24576);
}

// ---------------- aggregation dispatch (XCD-aware bijective block swizzle, T1/m204) ----------------
__global__ __launch_bounds__(256) void agg_kernel(const unsigned short* __restrict__ fsb,
                                                  const unsigned short* __restrict__ fdb,
                                                  unsigned short* __restrict__ hb,
                                                  const int* __restrict__ offs,
                                                  const int* __restrict__ cnt,
                                                  const int* __restrict__ csr_src,
                                                  const float* __restrict__ attn_l) {
    // Map round-robin XCD placement to contiguous node chunks per XCD: the
    // gather working set (src buckets) then lives in ONE XCD's L2 instead of 8.
    int nwg = gridDim.x;                 // 2500 (not %8) -> bijective variant
    int q = nwg >> 3, r = nwg & 7;
    int xcd = blockIdx.x & 7, idx = blockIdx.x >> 3;
    int u = (xcd < r) ? xcd * (q + 1) + idx
                      : r * (q + 1) + (xcd - r) * q + idx;
    agg_unit(u, threadIdx.x, fsb, fdb, hb, offs, cnt, csr_src, attn_l);
}

// ---------------- D9: fused pool + classifier (one block per graph) ----------------
__global__ __launch_bounds__(256) void poolcls_kernel(
    const unsigned short* __restrict__ hb, const int* __restrict__ gid,
    const float* __restrict__ Wc1, const float* __restrict__ bc1,
    const float* __restrict__ Wc2, const float* __restrict__ bc2,
    const float* __restrict__ Wc3, const float* __restrict__ bc3,
    float* __restrict__ out) {
    __shared__ float part[8 * HID];
    __shared__ float xin[HID];
    __shared__ float x1[HID];
    __shared__ float x2[HID / 2];
    int g = blockIdx.x, t = threadIdx.x;

    int lo = 0, hi = N_NODES;
    while (lo < hi) { int mid = (lo + hi) >> 1; if (gid[mid] < g) lo = mid + 1; else hi = mid; }
    int s0 = lo;
    hi = N_NODES;
    while (lo < hi) { int mid = (lo + hi) >> 1; if (gid[mid] < g + 1) lo = mid + 1; else hi = mid; }
    int e0 = lo;

    int r = t >> 5;
    int fb = (t & 31) * 8;
    float a0[8], a1[8];
#pragma unroll
    for (int j = 0; j < 8; ++j) { a0[j] = 0.f; a1[j] = 0.f; }
    int n = s0 + r;
    for (; n + 8 < e0; n += 16) {
        uint4 u0 = *(const uint4*)(hb + (size_t)n * HID + fb);
        uint4 u1 = *(const uint4*)(hb + (size_t)(n + 8) * HID + fb);
        float f0[8], f1[8];
        unpack8(u0, f0); unpack8(u1, f1);
#pragma unroll
        for (int j = 0; j < 8; ++j) { a0[j] += f0[j]; a1[j] += f1[j]; }
    }
    if (n < e0) {
        uint4 u0 = *(const uint4*)(hb + (size_t)n * HID + fb);
        float f0[8];
        unpack8(u0, f0);
#pragma unroll
        for (int j = 0; j < 8; ++j) a0[j] += f0[j];
    }
#pragma unroll
    for (int j = 0; j < 8; ++j) part[r * HID + fb + j] = a0[j] + a1[j];
    __syncthreads();
    {
        float s = 0.f;
#pragma unroll
        for (int r2 = 0; r2 < 8; ++r2) s += part[r2 * HID + t];
        xin[t] = s;
    }
    __syncthreads();

    {
        float acc = bc1[t];
        for (int k = 0; k < HID; ++k) acc += xin[k] * Wc1[k * HID + t];
        x1[t] = fmaxf(acc, 0.f);
    }
    __syncthreads();
    if (t < HID / 2) {
        float acc = bc2[t];
        for (int k = 0; k < HID; ++k) acc += x1[k] * Wc2[k * (HID / 2) + t];
        x2[t] = fmaxf(acc, 0.f);
    }
    __syncthreads();
    if (t < OUT_DIM) {
        float acc = bc3[t];
        for (int k = 0; k < HID / 2; ++k) acc += x2[k] * Wc3[k * OUT_DIM + t];
        out[g * OUT_DIM + t] = acc;
    }
}

// ---------------- launch: 10 dispatches (memset + 9 kernels) ----------------
extern "C" void kernel_launch(void* const* d_in, const int* in_sizes, int n_in,
                              void* d_out, int out_size, void* d_ws, size_t ws_size,
                              hipStream_t stream) {
    const float* feature = (const float*)d_in[0];
    const float* W_in   = (const float*)d_in[1];
    const float* b_in   = (const float*)d_in[2];
    const float* W_src  = (const float*)d_in[3];
    const float* b_src  = (const float*)d_in[4];
    const float* W_dst  = (const float*)d_in[5];
    const float* b_dst  = (const float*)d_in[6];
    const float* attn   = (const float*)d_in[7];
    const float* Wc1    = (const float*)d_in[8];
    const float* bc1    = (const float*)d_in[9];
    const float* Wc2    = (const float*)d_in[10];
    const float* bc2    = (const float*)d_in[11];
    const float* Wc3    = (const float*)d_in[12];
    const float* bc3    = (const float*)d_in[13];
    const int* src     = (const int*)d_in[14];
    const int* dst     = (const int*)d_in[15];
    const int* gid     = (const int*)d_in[16];
    float* out = (float*)d_out;

    char* w = (char*)d_ws;
    auto alloc = [&](size_t bytes) -> void* {
        void* p = (void*)w;
        w += (bytes + 255) & ~(size_t)255;
        return p;
    };
    unsigned short* hb  = (unsigned short*)alloc((size_t)N_NODES * HID * 2);  // unified bf16 h
    unsigned short* fsb = (unsigned short*)alloc((size_t)N_NODES * HID * 2);
    unsigned short* fdb = (unsigned short*)alloc((size_t)N_NODES * HID * 2);
    int* cnt     = (int*)alloc((size_t)N_BINS * 4);   // cnt + cglob zeroed by one memset
    int* cglob   = (int*)alloc(4);
    int* offs    = (int*)alloc((size_t)(N_BINS + 4) * 4);
    int* cursor  = (int*)alloc((size_t)N_BINS * 4);
    int* csr_src = (int*)alloc((size_t)N_EDGES * 4);
    unsigned short* WinT = (unsigned short*)alloc((size_t)IN_DIM * HID * 2);
    unsigned short* WT   = (unsigned short*)alloc((size_t)6 * HID * HID * 2);
    unsigned short* featH = (unsigned short*)alloc((size_t)N_NODES * IN_DIM * 2);
    (void)alloc(4096);  // slack for clamped staging overreach

    // D0: zero cnt + cglob (contiguous region, one memset)
    size_t zlen = (size_t)((char*)offs - (char*)cnt);
    hipMemsetAsync(cnt, 0, zlen, stream);

    // D1: prep (feature cast + weight transposes) || edge-bin count
    hipLaunchKernelGGL(prep_count_kernel, dim3(PREP_BLOCKS + COUNT_BLOCKS), dim3(256), 0, stream,
                       feature, W_in, W_src, W_dst, featH, WinT, WT, src, dst, cnt);

    // D2: input-projection GEMM || wide chunk scan (99 blocks, 1 atomic each)
    hipLaunchKernelGGL(gemm0_scan_kernel, dim3(GEMM_TILES + N_CHUNKS), dim3(256), 0, stream,
                       featH, WinT, b_in, hb, cnt, cglob, offs, cursor);

    // D3: layer-0 dual GEMM || CSR fill
    hipLaunchKernelGGL(gemm1_fill_kernel, dim3(GEMM_TILES + COUNT_BLOCKS), dim3(256), 0, stream,
                       hb, WT, b_src, fsb, WT + 3 * 65536, b_dst, fdb,
                       src, dst, cursor, csr_src);

    // D4..D8: agg0, gemm_l1, agg1, gemm_l2, agg2
    for (int l = 0; l < LAYERS; ++l) {
        hipLaunchKernelGGL(agg_kernel, dim3(N_NODES / 8), dim3(256), 0, stream,
                           fsb, fdb, hb, offs, cnt, csr_src, attn + (size_t)l * HEADS * DH);
        if (l + 1 < LAYERS) {
            hipLaunchKernelGGL(gemm_kernel, dim3(313, 2), dim3(256), 0, stream,
                               hb, WT + (size_t)(l + 1) * 65536, b_src + (size_t)(l + 1) * HID, fsb,
                               WT + (size_t)(4 + l) * 65536, b_dst + (size_t)(l + 1) * HID, fdb);
        }
    }

    // D9: fused graph-sum-pool + classifier
    hipLaunchKernelGGL(poolcls_kernel, dim3(NUM_GRAPHS), dim3(256), 0, stream,
                       hb, gid, Wc1, bc1, Wc2, bc2, Wc3, bc3, out);
}

// Round 6
// 314.581 us; speedup vs baseline: 2.0108x; 1.0052x over previous
//
#include <hip/hip_runtime.h>
#include <hip/hip_bf16.h>
#include <math.h>

#define N_NODES 20000
#define N_EDGES 320000
#define IN_DIM 128
#define HID 256
#define HEADS 8
#define DH 32
#define LAYERS 3
#define NUM_GRAPHS 64
#define OUT_DIM 10
#define SLOPE 0.2f

// src-bucketed CSR: bucket = src >> 12 (4096 nodes = 2 MB of fsb per bucket)
#define NBKT 5
#define N_BINS (N_NODES * NBKT)      // 100000
#define N_BINS4 (N_BINS / 4)         // 25000

// scan chunks aligned to node boundaries: 1020 bins = 204 nodes * 5 buckets.
#define CHUNK_I4 255                 // int4s per chunk (1020 bins)
#define N_CHUNKS 99                  // ceil(100000 / 1020)

#define GEMM_TILES 626               // 313 m-tiles x 2 n-tiles
#define COUNT_BLOCKS 1250            // 320000 / 256

typedef __bf16 bf16x8 __attribute__((ext_vector_type(8)));
typedef float f32x4 __attribute__((ext_vector_type(4)));

static __device__ __forceinline__ unsigned short f2bfbits(float v) {
    __bf16 b = (__bf16)v;
    return __builtin_bit_cast(unsigned short, b);
}
// unpack 8 bf16 (in a uint4) -> 8 fp32, exact
static __device__ __forceinline__ void unpack8(uint4 u, float* f) {
    unsigned p0 = u.x, p1 = u.y, p2 = u.z, p3 = u.w;
    f[0] = __builtin_bit_cast(float, p0 << 16);
    f[1] = __builtin_bit_cast(float, p0 & 0xffff0000u);
    f[2] = __builtin_bit_cast(float, p1 << 16);
    f[3] = __builtin_bit_cast(float, p1 & 0xffff0000u);
    f[4] = __builtin_bit_cast(float, p2 << 16);
    f[5] = __builtin_bit_cast(float, p2 & 0xffff0000u);
    f[6] = __builtin_bit_cast(float, p3 << 16);
    f[7] = __builtin_bit_cast(float, p3 & 0xffff0000u);
}

// async 16B global->LDS (DMA, wave-uniform LDS base + lane*16)
typedef const __attribute__((address_space(1))) unsigned int* as1_u32p;
typedef __attribute__((address_space(3))) unsigned int* as3_u32p;
static __device__ __forceinline__ void async_cp16(const unsigned short* g, unsigned short* l) {
    __builtin_amdgcn_global_load_lds((as1_u32p)g, (as3_u32p)l, 16, 0, 0);
}

// ---------------- prep: feature cast, weight transpose/cast ----------------
#define CAST_N4 (N_NODES * IN_DIM / 4)                 // 640000
#define WTRANS_TOTAL (IN_DIM * HID + 6 * HID * HID)    // 425984
#define PREP_TOTAL (CAST_N4 + WTRANS_TOTAL)            // 1065984 = 4164 * 256
#define PREP_BLOCKS (PREP_TOTAL / 256)                 // 4164 (exact)

static __device__ void prep_item(int idx,
                                 const float* __restrict__ feat,
                                 const float* __restrict__ Win,
                                 const float* __restrict__ Wsrc,
                                 const float* __restrict__ Wdst,
                                 unsigned short* __restrict__ featH,
                                 unsigned short* __restrict__ WinT,
                                 unsigned short* __restrict__ WT) {
    if (idx < CAST_N4) {
        float4 v = ((const float4*)feat)[idx];
        ushort4 o;
        o.x = f2bfbits(v.x); o.y = f2bfbits(v.y);
        o.z = f2bfbits(v.z); o.w = f2bfbits(v.w);
        ((ushort4*)featH)[idx] = o;
    } else {
        int j = idx - CAST_N4;
        if (j < IN_DIM * HID) {
            int n = j / IN_DIM, k = j % IN_DIM;
            WinT[j] = f2bfbits(Win[k * HID + n]);
        } else {
            int r6 = j - IN_DIM * HID;
            int mat = r6 >> 16;
            int r = r6 & 65535;
            int n = r >> 8, k = r & 255;
            const float* base = (mat < 3) ? (Wsrc + (size_t)mat * 65536)
                                          : (Wdst + (size_t)(mat - 3) * 65536);
            WT[r6] = f2bfbits(base[k * 256 + n]);
        }
    }
}

// ---------------- wide scan: block u scans its 1020-bin chunk; base via one atomicAdd ----------------
static __device__ void scans_unit(int u, int t, const int* __restrict__ cnt,
                                  int* __restrict__ cglob, int* __restrict__ offs,
                                  int* __restrict__ cursor, int* si) {
    int idx4 = u * CHUNK_I4 + t;               // t in [0,256); active t < 255
    bool act = (t < CHUNK_I4) && (idx4 < N_BINS4);
    int4 x = make_int4(0, 0, 0, 0);
    if (act) x = ((const int4*)cnt)[idx4];
    int tsum = x.x + x.y + x.z + x.w;
    int v = tsum;
#pragma unroll
    for (int d = 1; d < 64; d <<= 1) {
        int w = __shfl_up(v, d, 64);
        if ((t & 63) >= d) v += w;
    }
    if ((t & 63) == 63) si[4 + (t >> 6)] = v;
    __syncthreads();
    if (t == 0) {
        int S = si[4] + si[5] + si[6] + si[7];
        si[0] = atomicAdd(cglob, S);           // 99 atomics total -- no contention
    }
    __syncthreads();
    int base = si[0];
    int wid = t >> 6;
    int waveoff = 0;
    if (wid > 0) waveoff += si[4];
    if (wid > 1) waveoff += si[5];
    if (wid > 2) waveoff += si[6];
    int ex = base + waveoff + (v - tsum);
    if (act) {
        int4 o;
        o.x = ex; o.y = ex + x.x; o.z = o.y + x.y; o.w = o.z + x.z;
        ((int4*)offs)[idx4] = o;
        ((int4*)cursor)[idx4] = o;
    }
}

// ---------------- MFMA GEMM tile: M64 x N128, BK=32, register-direct A ----------------
// A fragments are plain 16B global loads (lane frag = A[row][k0 + quad*8 .. +8]),
// software-prefetched one K-step ahead -> A never touches LDS and never waits on
// the per-step barrier drain. LDS holds only double-buffered B panels:
// 16 KB (single) / 32 KB (dual) -> 4 blocks/CU (vs 2 at 64 KB), 16 waves/CU.
template <int DUAL>
static __device__ void gemm_tile(int mt, int nt, int t,
                                 const unsigned short* __restrict__ Ah,
                                 const unsigned short* __restrict__ BT1,
                                 const float* __restrict__ bias1,
                                 unsigned short* __restrict__ O1,
                                 const unsigned short* __restrict__ BT2,
                                 const float* __restrict__ bias2,
                                 unsigned short* __restrict__ O2,
                                 int M, int K, int N,
                                 unsigned short* Bs1P, unsigned short* Bs2P) {
    const int wv = t >> 6, lane = t & 63, quad = lane >> 4, l15 = lane & 15;
    const int m0 = mt * 64, n0 = nt * 128;

    // B staging (byte-identical to proven path)
    const int sB0 = wv * 64 + lane, sB1v = sB0 + 256;
    const int rB0 = sB0 >> 2, cB0 = (sB0 & 3) ^ ((rB0 >> 1) & 3);
    const int rB1 = sB1v >> 2, cB1 = (sB1v & 3) ^ ((rB1 >> 1) & 3);
    const size_t offB0 = (size_t)(n0 + rB0) * K + cB0 * 8;
    const size_t offB1 = (size_t)(n0 + rB1) * K + cB1 * 8;

    auto issueB = [&](int buf, int k0) {
        async_cp16(BT1 + offB0 + k0, Bs1P + buf * 4096 + wv * 512);
        async_cp16(BT1 + offB1 + k0, Bs1P + buf * 4096 + 2048 + wv * 512);
        if (DUAL) {
            async_cp16(BT2 + offB0 + k0, Bs2P + buf * 4096 + wv * 512);
            async_cp16(BT2 + offB1 + k0, Bs2P + buf * 4096 + 2048 + wv * 512);
        }
    };

    const int mrow0 = (wv >> 1) * 32;
    const int ncb = (wv & 1) * 64;

    // A direct-load row pointers (clamped; clamped rows' results are discarded)
    int r0 = m0 + mrow0 + l15;      if (r0 >= M) r0 = M - 1;
    int r1 = m0 + mrow0 + 16 + l15; if (r1 >= M) r1 = M - 1;
    const unsigned short* Ap0 = Ah + (size_t)r0 * K + quad * 8;
    const unsigned short* Ap1 = Ah + (size_t)r1 * K + quad * 8;

    f32x4 zero = {0.f, 0.f, 0.f, 0.f};
    f32x4 acc1[2][4], acc2[2][4];
#pragma unroll
    for (int mi = 0; mi < 2; ++mi)
#pragma unroll
        for (int t4 = 0; t4 < 4; ++t4) { acc1[mi][t4] = zero; acc2[mi][t4] = zero; }

    issueB(0, 0);
    bf16x8 aC0 = __builtin_bit_cast(bf16x8, *(const uint4*)(Ap0));
    bf16x8 aC1 = __builtin_bit_cast(bf16x8, *(const uint4*)(Ap1));

    int buf = 0;
    for (int k0 = 0; k0 < K; k0 += 32, buf ^= 1) {
        __syncthreads();
        bf16x8 aN0 = aC0, aN1 = aC1;
        if (k0 + 32 < K) {
            issueB(buf ^ 1, k0 + 32);
            aN0 = __builtin_bit_cast(bf16x8, *(const uint4*)(Ap0 + k0 + 32));
            aN1 = __builtin_bit_cast(bf16x8, *(const uint4*)(Ap1 + k0 + 32));
        }
#pragma unroll
        for (int t4 = 0; t4 < 4; ++t4) {
            int brow = ncb + t4 * 16 + l15;
            int boff = brow * 32 + ((quad ^ ((brow >> 1) & 3)) << 3);
            bf16x8 b1 = __builtin_bit_cast(bf16x8, *(const uint4*)(Bs1P + buf * 4096 + boff));
            acc1[0][t4] = __builtin_amdgcn_mfma_f32_16x16x32_bf16(aC0, b1, acc1[0][t4], 0, 0, 0);
            acc1[1][t4] = __builtin_amdgcn_mfma_f32_16x16x32_bf16(aC1, b1, acc1[1][t4], 0, 0, 0);
            if (DUAL) {
                bf16x8 b2 = __builtin_bit_cast(bf16x8, *(const uint4*)(Bs2P + buf * 4096 + boff));
                acc2[0][t4] = __builtin_amdgcn_mfma_f32_16x16x32_bf16(aC0, b2, acc2[0][t4], 0, 0, 0);
                acc2[1][t4] = __builtin_amdgcn_mfma_f32_16x16x32_bf16(aC1, b2, acc2[1][t4], 0, 0, 0);
            }
        }
        aC0 = aN0; aC1 = aN1;
    }

    float bia1[4], bia2[4];
#pragma unroll
    for (int t4 = 0; t4 < 4; ++t4) {
        bia1[t4] = bias1[n0 + ncb + t4 * 16 + l15];
        bia2[t4] = DUAL ? bias2[n0 + ncb + t4 * 16 + l15] : 0.f;
    }
#pragma unroll
    for (int mi = 0; mi < 2; ++mi) {
#pragma unroll
        for (int t4 = 0; t4 < 4; ++t4) {
            int gn = n0 + ncb + t4 * 16 + l15;
#pragma unroll
            for (int r = 0; r < 4; ++r) {
                int gm = m0 + mrow0 + mi * 16 + quad * 4 + r;
                if (gm < M) {
                    float v = acc1[mi][t4][r] + bia1[t4];
                    O1[(size_t)gm * N + gn] = f2bfbits(v);
                    if (DUAL) {
                        float v2 = acc2[mi][t4][r] + bia2[t4];
                        O2[(size_t)gm * N + gn] = f2bfbits(v2);
                    }
                }
            }
        }
    }
}

// ---------------- GATv2 aggregation (proven code; end from offs+cnt) ----------------
static __device__ void agg_unit(int u, int t,
                                const unsigned short* __restrict__ fsb,
                                const unsigned short* __restrict__ fdb,
                                unsigned short* __restrict__ hb,
                                const int* __restrict__ offs,
                                const int* __restrict__ cnt,
                                const int* __restrict__ csr_src,
                                const float* __restrict__ attn_l) {
    int node = u * 8 + (t >> 5);
    if (node >= N_NODES) return;
    int l32 = t & 31;
    int dbase = l32 * 8;
    int abase = (l32 >> 2) * DH + (l32 & 3) * 8;

    float a[8];
#pragma unroll
    for (int j = 0; j < 8; ++j) a[j] = attn_l[abase + j];

    float fdv[8];
    unpack8(*(const uint4*)(fdb + (size_t)node * HID + dbase), fdv);

    float ssum0 = 0.f, ssum1 = 0.f;
    float acc0[8], acc1[8];
#pragma unroll
    for (int j = 0; j < 8; ++j) { acc0[j] = 0.f; acc1[j] = 0.f; }

    auto procE = [&](uint4 uu, float* acc, float& ssum) {
        float fsv[8];
        unpack8(uu, fsv);
        float p = 0.f;
#pragma unroll
        for (int j = 0; j < 8; ++j) {
            float e = fsv[j] + fdv[j];
            e = fmaxf(e, SLOPE * e);   // leakyrelu (slope<1)
            p += e * a[j];
        }
        p += __shfl_xor(p, 1, 64);
        p += __shfl_xor(p, 2, 64);
        float w = __expf(p);
        ssum += w;
#pragma unroll
        for (int j = 0; j < 8; ++j) acc[j] += w * fsv[j];
    };

    const unsigned short* fsl = fsb + dbase;
    int b0 = node * NBKT;
    int beg = offs[b0];
    int end = offs[b0 + NBKT - 1] + cnt[b0 + NBKT - 1];  // chunk-local contiguity
    int nfull = (end - beg) >> 2;
    const int limit = beg + nfull * 4;

    uint4 cu0, cu1, cu2, cu3;
    int ci0, ci1, ci2, ci3;
    int base = beg + 8;
    bool have = (nfull >= 1);
    bool haveN = (nfull >= 2);
    if (have) {
        int s0 = csr_src[beg], s1 = csr_src[beg + 1];
        int s2 = csr_src[beg + 2], s3 = csr_src[beg + 3];
        if (haveN) {
            ci0 = csr_src[beg + 4]; ci1 = csr_src[beg + 5];
            ci2 = csr_src[beg + 6]; ci3 = csr_src[beg + 7];
        }
        cu0 = *(const uint4*)(fsl + (size_t)s0 * HID);
        cu1 = *(const uint4*)(fsl + (size_t)s1 * HID);
        cu2 = *(const uint4*)(fsl + (size_t)s2 * HID);
        cu3 = *(const uint4*)(fsl + (size_t)s3 * HID);
    }
    while (have) {
        uint4 nu0, nu1, nu2, nu3;
        int ni0, ni1, ni2, ni3;
        if (haveN) {
            nu0 = *(const uint4*)(fsl + (size_t)ci0 * HID);
            nu1 = *(const uint4*)(fsl + (size_t)ci1 * HID);
            nu2 = *(const uint4*)(fsl + (size_t)ci2 * HID);
            nu3 = *(const uint4*)(fsl + (size_t)ci3 * HID);
        }
        bool haveNN = (base + 4 <= limit);
        if (haveNN) {
            ni0 = csr_src[base]; ni1 = csr_src[base + 1];
            ni2 = csr_src[base + 2]; ni3 = csr_src[base + 3];
        }
        base += 4;
        procE(cu0, acc0, ssum0);
        procE(cu1, acc1, ssum1);
        procE(cu2, acc0, ssum0);
        procE(cu3, acc1, ssum1);
        if (haveN) { cu0 = nu0; cu1 = nu1; cu2 = nu2; cu3 = nu3; }
        if (haveNN) { ci0 = ni0; ci1 = ni1; ci2 = ni2; ci3 = ni3; }
        have = haveN; haveN = haveNN;
    }
    for (int idx = limit; idx < end; ++idx) {
        int sv = csr_src[idx];
        procE(*(const uint4*)(fsl + (size_t)sv * HID), acc0, ssum0);
    }

    float ssum = ssum0 + ssum1;
    float acc[8];
#pragma unroll
    for (int j = 0; j < 8; ++j) acc[j] = acc0[j] + acc1[j];

    float inv = ssum > 0.f ? 1.f / ssum : 0.f;
    float hv[8];
    unpack8(*(const uint4*)(hb + (size_t)node * HID + dbase), hv);
    unsigned short ob[8];
#pragma unroll
    for (int j = 0; j < 8; ++j) {
        float o = fmaxf(acc[j] * inv + hv[j], 0.f);
        ob[j] = f2bfbits(o);
    }
    *(uint4*)(hb + (size_t)node * HID + dbase) = *(uint4*)ob;
}

// ---------------- D1: prep || count ----------------
__global__ void prep_count_kernel(const float* __restrict__ feat,
                                  const float* __restrict__ Win,
                                  const float* __restrict__ Wsrc,
                                  const float* __restrict__ Wdst,
                                  unsigned short* __restrict__ featH,
                                  unsigned short* __restrict__ WinT,
                                  unsigned short* __restrict__ WT,
                                  const int* __restrict__ src,
                                  const int* __restrict__ dst,
                                  int* __restrict__ cnt) {
    int bid = blockIdx.x;
    if (bid < PREP_BLOCKS) {
        prep_item(bid * 256 + threadIdx.x, feat, Win, Wsrc, Wdst, featH, WinT, WT);
    } else {
        int e = (bid - PREP_BLOCKS) * 256 + threadIdx.x;
        if (e < N_EDGES) atomicAdd(&cnt[dst[e] * NBKT + (src[e] >> 12)], 1);
    }
}

// ---------------- D2: input-projection GEMM || wide chunk scan ----------------
// regA, DUAL=0: LDS = B dbuf only = 16 KB
__global__ __launch_bounds__(256, 4) void gemm0_scan_kernel(
    const unsigned short* __restrict__ featH, const unsigned short* __restrict__ WinT,
    const float* __restrict__ b_in, unsigned short* __restrict__ hb,
    const int* __restrict__ cnt, int* __restrict__ cglob,
    int* __restrict__ offs, int* __restrict__ cursor) {
    __shared__ __align__(16) unsigned short smem[8192];
    int bid = blockIdx.x;
    if (bid < GEMM_TILES) {
        gemm_tile<0>(bid >> 1, bid & 1, threadIdx.x, featH, WinT, b_in, hb,
                     (const unsigned short*)nullptr, (const float*)nullptr,
                     (unsigned short*)nullptr, N_NODES, IN_DIM, HID,
                     smem, smem);
    } else {
        scans_unit(bid - GEMM_TILES, threadIdx.x, cnt, cglob, offs, cursor,
                   (int*)(void*)smem);
    }
}

// ---------------- D3: layer-0 dual GEMM || CSR fill ----------------
// regA, DUAL=1: LDS = 2 x B dbuf = 32 KB -> 4 blocks/CU
__global__ __launch_bounds__(256, 4) void gemm1_fill_kernel(
    const unsigned short* __restrict__ hb,
    const unsigned short* __restrict__ WTs, const float* __restrict__ bs,
    unsigned short* __restrict__ fsb,
    const unsigned short* __restrict__ WTd, const float* __restrict__ bd,
    unsigned short* __restrict__ fdb,
    const int* __restrict__ src, const int* __restrict__ dst,
    int* __restrict__ cursor, int* __restrict__ csr_src) {
    __shared__ __align__(16) unsigned short smem[16384];
    int bid = blockIdx.x;
    if (bid < GEMM_TILES) {
        gemm_tile<1>(bid >> 1, bid & 1, threadIdx.x, hb, WTs, bs, fsb, WTd, bd, fdb,
                     N_NODES, HID, HID, smem, smem + 8192);
    } else {
        int e = (bid - GEMM_TILES) * 256 + threadIdx.x;
        if (e < N_EDGES) {
            int sv = src[e];
            int p = atomicAdd(&cursor[dst[e] * NBKT + (sv >> 12)], 1);
            csr_src[p] = sv;
        }
    }
}

// ---------------- standalone dual GEMM (layers 1,2) ----------------
__global__ __launch_bounds__(256, 4) void gemm_kernel(
    const unsigned short* __restrict__ Ah,
    const unsigned short* __restrict__ BT1, const float* __restrict__ bias1,
    unsigned short* __restrict__ O1,
    const unsigned short* __restrict__ BT2, const float* __restrict__ bias2,
    unsigned short* __restrict__ O2) {
    __shared__ __align__(16) unsigned short smem[16384];
    gemm_tile<1>(blockIdx.x, blockIdx.y, threadIdx.x, Ah, BT1, bias1, O1,
                 BT2, bias2, O2, N_NODES, HID, HID, smem, smem + 8192);
}

// ---------------- aggregation dispatch (XCD-aware bijective block swizzle, T1/m204) ----------------
__global__ __launch_bounds__(256) void agg_kernel(const unsigned short* __restrict__ fsb,
                                                  const unsigned short* __restrict__ fdb,
                                                  unsigned short* __restrict__ hb,
                                                  const int* __restrict__ offs,
                                                  const int* __restrict__ cnt,
                                                  const int* __restrict__ csr_src,
                                                  const float* __restrict__ attn_l) {
    int nwg = gridDim.x;                 // 2500 (not %8) -> bijective variant
    int q = nwg >> 3, r = nwg & 7;
    int xcd = blockIdx.x & 7, idx = blockIdx.x >> 3;
    int u = (xcd < r) ? xcd * (q + 1) + idx
                      : r * (q + 1) + (xcd - r) * q + idx;
    agg_unit(u, threadIdx.x, fsb, fdb, hb, offs, cnt, csr_src, attn_l);
}

// ---------------- D9: fused pool + classifier (one block per graph) ----------------
__global__ __launch_bounds__(256) void poolcls_kernel(
    const unsigned short* __restrict__ hb, const int* __restrict__ gid,
    const float* __restrict__ Wc1, const float* __restrict__ bc1,
    const float* __restrict__ Wc2, const float* __restrict__ bc2,
    const float* __restrict__ Wc3, const float* __restrict__ bc3,
    float* __restrict__ out) {
    __shared__ float part[8 * HID];
    __shared__ float xin[HID];
    __shared__ float x1[HID];
    __shared__ float x2[HID / 2];
    int g = blockIdx.x, t = threadIdx.x;

    int lo = 0, hi = N_NODES;
    while (lo < hi) { int mid = (lo + hi) >> 1; if (gid[mid] < g) lo = mid + 1; else hi = mid; }
    int s0 = lo;
    hi = N_NODES;
    while (lo < hi) { int mid = (lo + hi) >> 1; if (gid[mid] < g + 1) lo = mid + 1; else hi = mid; }
    int e0 = lo;

    int r = t >> 5;
    int fb = (t & 31) * 8;
    float a0[8], a1[8];
#pragma unroll
    for (int j = 0; j < 8; ++j) { a0[j] = 0.f; a1[j] = 0.f; }
    int n = s0 + r;
    for (; n + 8 < e0; n += 16) {
        uint4 u0 = *(const uint4*)(hb + (size_t)n * HID + fb);
        uint4 u1 = *(const uint4*)(hb + (size_t)(n + 8) * HID + fb);
        float f0[8], f1[8];
        unpack8(u0, f0); unpack8(u1, f1);
#pragma unroll
        for (int j = 0; j < 8; ++j) { a0[j] += f0[j]; a1[j] += f1[j]; }
    }
    if (n < e0) {
        uint4 u0 = *(const uint4*)(hb + (size_t)n * HID + fb);
        float f0[8];
        unpack8(u0, f0);
#pragma unroll
        for (int j = 0; j < 8; ++j) a0[j] += f0[j];
    }
#pragma unroll
    for (int j = 0; j < 8; ++j) part[r * HID + fb + j] = a0[j] + a1[j];
    __syncthreads();
    {
        float s = 0.f;
#pragma unroll
        for (int r2 = 0; r2 < 8; ++r2) s += part[r2 * HID + t];
        xin[t] = s;
    }
    __syncthreads();

    {
        float acc = bc1[t];
        for (int k = 0; k < HID; ++k) acc += xin[k] * Wc1[k * HID + t];
        x1[t] = fmaxf(acc, 0.f);
    }
    __syncthreads();
    if (t < HID / 2) {
        float acc = bc2[t];
        for (int k = 0; k < HID; ++k) acc += x1[k] * Wc2[k * (HID / 2) + t];
        x2[t] = fmaxf(acc, 0.f);
    }
    __syncthreads();
    if (t < OUT_DIM) {
        float acc = bc3[t];
        for (int k = 0; k < HID / 2; ++k) acc += x2[k] * Wc3[k * OUT_DIM + t];
        out[g * OUT_DIM + t] = acc;
    }
}

// ---------------- launch: 10 dispatches (memset + 9 kernels) ----------------
extern "C" void kernel_launch(void* const* d_in, const int* in_sizes, int n_in,
                              void* d_out, int out_size, void* d_ws, size_t ws_size,
                              hipStream_t stream) {
    const float* feature = (const float*)d_in[0];
    const float* W_in   = (const float*)d_in[1];
    const float* b_in   = (const float*)d_in[2];
    const float* W_src  = (const float*)d_in[3];
    const float* b_src  = (const float*)d_in[4];
    const float* W_dst  = (const float*)d_in[5];
    const float* b_dst  = (const float*)d_in[6];
    const float* attn   = (const float*)d_in[7];
    const float* Wc1    = (const float*)d_in[8];
    const float* bc1    = (const float*)d_in[9];
    const float* Wc2    = (const float*)d_in[10];
    const float* bc2    = (const float*)d_in[11];
    const float* Wc3    = (const float*)d_in[12];
    const float* bc3    = (const float*)d_in[13];
    const int* src     = (const int*)d_in[14];
    const int* dst     = (const int*)d_in[15];
    const int* gid     = (const int*)d_in[16];
    float* out = (float*)d_out;

    char* w = (char*)d_ws;
    auto alloc = [&](size_t bytes) -> void* {
        void* p = (void*)w;
        w += (bytes + 255) & ~(size_t)255;
        return p;
    };
    unsigned short* hb  = (unsigned short*)alloc((size_t)N_NODES * HID * 2);  // unified bf16 h
    unsigned short* fsb = (unsigned short*)alloc((size_t)N_NODES * HID * 2);
    unsigned short* fdb = (unsigned short*)alloc((size_t)N_NODES * HID * 2);
    int* cnt     = (int*)alloc((size_t)N_BINS * 4);   // cnt + cglob zeroed by one memset
    int* cglob   = (int*)alloc(4);
    int* offs    = (int*)alloc((size_t)(N_BINS + 4) * 4);
    int* cursor  = (int*)alloc((size_t)N_BINS * 4);
    int* csr_src = (int*)alloc((size_t)N_EDGES * 4);
    unsigned short* WinT = (unsigned short*)alloc((size_t)IN_DIM * HID * 2);
    unsigned short* WT   = (unsigned short*)alloc((size_t)6 * HID * HID * 2);
    unsigned short* featH = (unsigned short*)alloc((size_t)N_NODES * IN_DIM * 2);
    (void)alloc(4096);  // slack for clamped staging overreach

    // D0: zero cnt + cglob (contiguous region, one memset)
    size_t zlen = (size_t)((char*)offs - (char*)cnt);
    hipMemsetAsync(cnt, 0, zlen, stream);

    // D1: prep (feature cast + weight transposes) || edge-bin count
    hipLaunchKernelGGL(prep_count_kernel, dim3(PREP_BLOCKS + COUNT_BLOCKS), dim3(256), 0, stream,
                       feature, W_in, W_src, W_dst, featH, WinT, WT, src, dst, cnt);

    // D2: input-projection GEMM || wide chunk scan (99 blocks, 1 atomic each)
    hipLaunchKernelGGL(gemm0_scan_kernel, dim3(GEMM_TILES + N_CHUNKS), dim3(256), 0, stream,
                       featH, WinT, b_in, hb, cnt, cglob, offs, cursor);

    // D3: layer-0 dual GEMM || CSR fill
    hipLaunchKernelGGL(gemm1_fill_kernel, dim3(GEMM_TILES + COUNT_BLOCKS), dim3(256), 0, stream,
                       hb, WT, b_src, fsb, WT + 3 * 65536, b_dst, fdb,
                       src, dst, cursor, csr_src);

    // D4..D8: agg0, gemm_l1, agg1, gemm_l2, agg2
    for (int l = 0; l < LAYERS; ++l) {
        hipLaunchKernelGGL(agg_kernel, dim3(N_NODES / 8), dim3(256), 0, stream,
                           fsb, fdb, hb, offs, cnt, csr_src, attn + (size_t)l * HEADS * DH);
        if (l + 1 < LAYERS) {
            hipLaunchKernelGGL(gemm_kernel, dim3(313, 2), dim3(256), 0, stream,
                               hb, WT + (size_t)(l + 1) * 65536, b_src + (size_t)(l + 1) * HID, fsb,
                               WT + (size_t)(4 + l) * 65536, b_dst + (size_t)(l + 1) * HID, fdb);
        }
    }

    // D9: fused graph-sum-pool + classifier
    hipLaunchKernelGGL(poolcls_kernel, dim3(NUM_GRAPHS), dim3(256), 0, stream,
                       hb, gid, Wc1, bc1, Wc2, bc2, Wc3, bc3, out);
}